// Round 7
// baseline (217.387 us; speedup 1.0000x reference)
//
#include <hip/hip_runtime.h>
#include <stdint.h>

#define HH 10
#define DD 64
#define LL 4096
#define CC 640
#define KVL 8192
#define ALPHA 0.42f
#define SPLIT 4
#define SC2 0.1803368801111204f  // (1/sqrt(64)) * log2(e)

typedef __attribute__((ext_vector_type(8))) short s16x8;
typedef __attribute__((ext_vector_type(4))) float f32x4;

__device__ inline ushort f2bf(float f) {
  uint32_t u = __builtin_bit_cast(uint32_t, f);
  u += 0x7FFFu + ((u >> 16) & 1u);   // RNE
  return (ushort)(u >> 16);
}

__device__ inline uint cvtpk(float lo, float hi) {
  uint r;
  asm("v_cvt_pk_bf16_f32 %0, %1, %2" : "=v"(r) : "v"(lo), "v"(hi));
  return r;
}

__device__ inline void gl16(const ushort* g, ushort* l) {
  __builtin_amdgcn_global_load_lds(
      (const __attribute__((address_space(1))) uint32_t*)g,
      (__attribute__((address_space(3))) uint32_t*)l, 16, 0, 0);
}

__device__ inline void bar() {
  __builtin_amdgcn_sched_barrier(0);
  __builtin_amdgcn_s_barrier();
  __builtin_amdgcn_sched_barrier(0);
}

// V^T tile column position for kv-local row kl (0..63), matching the
// register layout of the swapped-QK^T P fragment (see k_attn):
// A-slot s=8*lg+m (within 32-block k0) must hold kv = 32*k0+16*(m>>2)+4*lg+(m&3).
// Inverse: p = (kl&32) | ((kl&12)<<1) | ((kl&16)>>2) | (kl&3)
__device__ inline int vpos(int kl) {
  return (kl & 32) | ((kl & 12) << 1) | ((kl & 16) >> 2) | (kl & 3);
}

// ---------------- prep: hs fp32 -> bf16 ----------------
__global__ void k_cvt_hs(const float* __restrict__ in, ushort* __restrict__ out, int n4) {
  int i = blockIdx.x * blockDim.x + threadIdx.x;
  if (i < n4) {
    float4 v = ((const float4*)in)[i];
    ushort4 o;
    o.x = f2bf(v.x); o.y = f2bf(v.y); o.z = f2bf(v.z); o.w = f2bf(v.w);
    ((ushort4*)out)[i] = o;
  }
}

// ---------------- prep: W [K][N] fp32 -> WT [N][K] bf16 ----------------
__global__ void k_wT(const float* __restrict__ W, ushort* __restrict__ WT) {
  __shared__ ushort t[64][65];
  int k0 = blockIdx.x * 64, n0 = blockIdx.y * 64;
  int tid = threadIdx.x;
#pragma unroll
  for (int i = 0; i < 4; ++i) {
    int id = tid + i * 256;
    int r = id >> 4, c4 = id & 15;
    float4 v = *(const float4*)(W + (size_t)(k0 + r) * CC + n0 + c4 * 4);
    t[r][c4 * 4 + 0] = f2bf(v.x);
    t[r][c4 * 4 + 1] = f2bf(v.y);
    t[r][c4 * 4 + 2] = f2bf(v.z);
    t[r][c4 * 4 + 3] = f2bf(v.w);
  }
  __syncthreads();
#pragma unroll
  for (int i = 0; i < 2; ++i) {
    int id = tid + i * 256;
    int n = id >> 3, cc = id & 7;
    ushort tmp[8];
#pragma unroll
    for (int j = 0; j < 8; ++j) tmp[j] = t[cc * 8 + j][n];
    *(uint4*)(WT + (size_t)(n0 + n) * CC + k0 + cc * 8) = *(uint4*)tmp;
  }
}

// ---------------- prep: background KV (rows L..KVL-1) ----------------
__global__ void k_cvt_bg(const float* __restrict__ Kbg, const float* __restrict__ Vbg,
                         ushort* __restrict__ kb, ushort* __restrict__ vbT, int n4) {
  int i = blockIdx.x * blockDim.x + threadIdx.x;
  if (i >= n4) return;
  int e = i * 4;
  int h = e / (LL * DD);
  int rem = e - h * (LL * DD);
  int kvl = rem >> 6;        // local row 0..4095
  int d0 = rem & 63;         // multiple of 4
  int kv = LL + kvl;         // global kv row
  float4 kf = ((const float4*)Kbg)[i];
  float4 vf = ((const float4*)Vbg)[i];
  {  // K: row-swizzled 16B chunks
    int chunk = d0 >> 3, off = d0 & 7;
    size_t kdst = ((size_t)h * KVL + kv) * 64 + (size_t)(((chunk ^ (kv & 7)) << 3) + off);
    ushort4 ok;
    ok.x = f2bf(ALPHA * kf.x); ok.y = f2bf(ALPHA * kf.y);
    ok.z = f2bf(ALPHA * kf.z); ok.w = f2bf(ALPHA * kf.w);
    *(ushort4*)(kb + kdst) = ok;
  }
  {  // V^T tiles: position-permuted + swizzled
    int tile = kv >> 6, kl = kv & 63;
    int c = vpos(kl);
    size_t vbase = ((size_t)h * 128 + tile) * 4096;
    float vv[4] = {vf.x, vf.y, vf.z, vf.w};
#pragma unroll
    for (int j = 0; j < 4; ++j) {
      int d = d0 + j;
      vbT[vbase + d * 64 + (((c >> 3) ^ (d & 7)) << 3) + (c & 7)] = f2bf(ALPHA * vv[j]);
    }
  }
}

// ---------------- bf16 GEMM: C[M][N] = A[M][K] * BT[N][K]^T ----------------
// MODE 0: Q head layout, scaled by SC2  MODE 1: K row-swizzled
// MODE 2: V^T permuted tiles            MODE 3: fp32 + bias (final)
template <int MODE>
__global__ __launch_bounds__(512) void k_gemm(
    const ushort* __restrict__ A, const ushort* __restrict__ BT,
    ushort* __restrict__ outB, float* __restrict__ outF,
    const float* __restrict__ bias, int M, int Kd, int N, size_t headStride) {
  __shared__ uint4 As4[128 * 8];
  __shared__ uint4 Bs4[64 * 8];
  int tid = threadIdx.x;
  int m0 = blockIdx.x * 128, n0 = blockIdx.y * 64;
  int wid = tid >> 6, lane = tid & 63;
  int wr = wid >> 1, wc = wid & 1;
  int lr = lane & 15, lg = lane >> 4;
  f32x4 acc[2][2] = {};

  for (int kt = 0; kt < Kd; kt += 64) {
    __syncthreads();
    {
      int id = tid;
#pragma unroll
      for (int i = 0; i < 2; ++i, id += 512) {
        int r = id >> 3, cc = id & 7;
        uint4 v = *(const uint4*)(A + (size_t)(m0 + r) * Kd + kt + cc * 8);
        As4[r * 8 + (cc ^ (r & 7))] = v;
      }
      int r = tid >> 3, cc = tid & 7;
      uint4 v = *(const uint4*)(BT + (size_t)(n0 + r) * Kd + kt + cc * 8);
      Bs4[r * 8 + (cc ^ (r & 7))] = v;
    }
    __syncthreads();
#pragma unroll
    for (int k0 = 0; k0 < 2; ++k0) {
      s16x8 a[2], b[2];
#pragma unroll
      for (int i = 0; i < 2; ++i) {
        int r = wr * 32 + i * 16 + lr;
        a[i] = *(const s16x8*)&As4[r * 8 + ((k0 * 4 + lg) ^ (r & 7))];
      }
#pragma unroll
      for (int j = 0; j < 2; ++j) {
        int r = wc * 32 + j * 16 + lr;
        b[j] = *(const s16x8*)&Bs4[r * 8 + ((k0 * 4 + lg) ^ (r & 7))];
      }
#pragma unroll
      for (int i = 0; i < 2; ++i)
#pragma unroll
        for (int j = 0; j < 2; ++j)
          acc[i][j] = __builtin_amdgcn_mfma_f32_16x16x32_bf16(a[i], b[j], acc[i][j], 0, 0, 0);
    }
  }
#pragma unroll
  for (int i = 0; i < 2; ++i)
#pragma unroll
    for (int j = 0; j < 2; ++j)
#pragma unroll
      for (int q = 0; q < 4; ++q) {
        int m = m0 + wr * 32 + i * 16 + lg * 4 + q;
        int n = n0 + wc * 32 + j * 16 + lr;
        float v = acc[i][j][q];
        if (MODE == 3) {
          outF[(size_t)m * N + n] = v + bias[n];
        } else if (MODE == 0) {
          outB[(size_t)(n >> 6) * headStride + (size_t)m * 64 + (n & 63)] = f2bf(v * SC2);
        } else if (MODE == 1) {
          int d = n & 63;
          outB[(size_t)(n >> 6) * headStride + (size_t)m * 64 +
               (((d >> 3) ^ (m & 7)) << 3) + (d & 7)] = f2bf(v);
        } else {  // MODE 2: V^T tiles, permuted positions
          int d = n & 63, tile = m >> 6, kl = m & 63;
          int c = vpos(kl);
          outB[((size_t)(n >> 6) * 128 + tile) * 4096 + (size_t)d * 64 +
               (((c >> 3) ^ (d & 7)) << 3) + (c & 7)] = f2bf(v);
        }
      }
}

// ---------------- flash attention (KV-split, static max, in-register P) ----------------
// grid 640 = 16 qblocks x 10 heads x SPLIT, remapped so each XCD gets a
// contiguous span of 80 (5 KV slices, 2.5MB -> fits 4MB XCD L2).
// 512 threads = 8 waves, wave owns 32 q-rows, KVBLK=64.
// Swapped QK^T keeps P in registers; rowsum via ones-MFMA (free matrix pipe).
__global__ __launch_bounds__(512, 4) void k_attn(
    const ushort* __restrict__ qb,    // [H][L][64], pre-scaled by SC2
    const ushort* __restrict__ kb,    // [H][KVL][64] row-swizzled
    const ushort* __restrict__ vbT,   // [H][128][4096] V^T permuted tiles
    float* __restrict__ Op,           // [SPLIT][H][L][64] unnormalized
    float* __restrict__ lb) {         // [SPLIT][H][L] row sums
  __shared__ ushort Ks[2][4096];
  __shared__ ushort Vs[2][4096];

  int tid = threadIdx.x, wid = tid >> 6, lane = tid & 63;
  int lr = lane & 15, lg = lane >> 4;

  // XCD-contiguous remap: dispatch sends flat%8 to XCD flat%8; make each
  // XCD's set a contiguous logical span of 80 blocks.
  int flat = blockIdx.x;
  int f2 = (flat & 7) * 80 + (flat >> 3);
  int qblk = f2 & 15;
  int h = (f2 >> 4) % HH;
  int sp = f2 / (16 * HH);
  int q0 = qblk * 256 + wid * 32;

  // Q fragments: 2 row-blocks x 2 k-chunks (B-operand layout: lane -> Q[row=lr][d=lg*8..])
  s16x8 qa[2][2];
#pragma unroll
  for (int i = 0; i < 2; ++i) {
    const ushort* qptr = qb + ((size_t)h * LL + q0 + i * 16 + lr) * DD + lg * 8;
    qa[i][0] = *(const s16x8*)qptr;
    qa[i][1] = *(const s16x8*)(qptr + 32);
  }

  // ones B-fragment for rowsum MFMA
  s16x8 ones;
#pragma unroll
  for (int i = 0; i < 8; ++i) ones[i] = (short)0x3F80;

  f32x4 o[2][4] = {};
  f32x4 ol[2] = {};

  const int t0 = sp * (KVL / SPLIT / 64), NT = KVL / SPLIT / 64;
  const ushort* kh = kb + (size_t)h * KVL * DD + (size_t)t0 * 4096;
  const ushort* vh = vbT + (size_t)h * 128 * 4096 + (size_t)t0 * 4096;

  // prologue: stage tile 0 (1 K + 1 V gl16 per thread), wait, sync
  gl16(kh + tid * 8, &Ks[0][tid * 8]);
  gl16(vh + tid * 8, &Vs[0][tid * 8]);
  asm volatile("s_waitcnt vmcnt(0)" ::: "memory");
  bar();

  for (int t = 0; t < NT; ++t) {
    if (t < NT - 1) {
      int nb = (t + 1) & 1;
      gl16(kh + (size_t)(t + 1) * 4096 + tid * 8, &Ks[nb][tid * 8]);
      gl16(vh + (size_t)(t + 1) * 4096 + tid * 8, &Vs[nb][tid * 8]);
    }

    const ushort* Kc = Ks[t & 1];
    const ushort* Vc = Vs[t & 1];

    // S^T = K Q^T : 16 MFMA. Lane (lg,lr), reg r of s[i][j]:
    //   S[q = q0+i*16+lr][kv = t*64 + j*16 + lg*4 + r]
    f32x4 s[2][4] = {};
    __builtin_amdgcn_s_setprio(1);
#pragma unroll
    for (int k0 = 0; k0 < 2; ++k0) {
#pragma unroll
      for (int j = 0; j < 4; ++j) {
        int r = j * 16 + lr;
        s16x8 kf = *(const s16x8*)&Kc[r * 64 + (((k0 * 4 + lg) ^ (r & 7)) << 3)];
        s[0][j] = __builtin_amdgcn_mfma_f32_16x16x32_bf16(kf, qa[0][k0], s[0][j], 0, 0, 0);
        s[1][j] = __builtin_amdgcn_mfma_f32_16x16x32_bf16(kf, qa[1][k0], s[1][j], 0, 0, 0);
      }
    }
    __builtin_amdgcn_s_setprio(0);

    // P = exp2(S) (Q pre-scaled, static max), pack to bf16 pairs in-register
    uint w[2][4][2];
#pragma unroll
    for (int i = 0; i < 2; ++i) {
#pragma unroll
      for (int j = 0; j < 4; ++j)
#pragma unroll
        for (int q = 0; q < 4; ++q)
          s[i][j][q] = exp2f(s[i][j][q]);
#pragma unroll
      for (int j = 0; j < 4; ++j) {
        w[i][j][0] = cvtpk(s[i][j][0], s[i][j][1]);
        w[i][j][1] = cvtpk(s[i][j][2], s[i][j][3]);
      }
    }

    // O += P V (16 MFMA) and rowsum l += P·1 (4 MFMA)
    __builtin_amdgcn_s_setprio(1);
#pragma unroll
    for (int k0 = 0; k0 < 2; ++k0) {
      uint4 u0, u1;
      u0.x = w[0][2 * k0][0]; u0.y = w[0][2 * k0][1];
      u0.z = w[0][2 * k0 + 1][0]; u0.w = w[0][2 * k0 + 1][1];
      u1.x = w[1][2 * k0][0]; u1.y = w[1][2 * k0][1];
      u1.z = w[1][2 * k0 + 1][0]; u1.w = w[1][2 * k0 + 1][1];
      s16x8 pa0 = __builtin_bit_cast(s16x8, u0);
      s16x8 pa1 = __builtin_bit_cast(s16x8, u1);
      ol[0] = __builtin_amdgcn_mfma_f32_16x16x32_bf16(pa0, ones, ol[0], 0, 0, 0);
      ol[1] = __builtin_amdgcn_mfma_f32_16x16x32_bf16(pa1, ones, ol[1], 0, 0, 0);
#pragma unroll
      for (int j = 0; j < 4; ++j) {
        int r = j * 16 + lr;  // d row in V^T
        s16x8 bv = *(const s16x8*)&Vc[r * 64 + (((k0 * 4 + lg) ^ (r & 7)) << 3)];
        o[0][j] = __builtin_amdgcn_mfma_f32_16x16x32_bf16(pa0, bv, o[0][j], 0, 0, 0);
        o[1][j] = __builtin_amdgcn_mfma_f32_16x16x32_bf16(pa1, bv, o[1][j], 0, 0, 0);
      }
    }
    __builtin_amdgcn_s_setprio(0);

    asm volatile("s_waitcnt vmcnt(0)" ::: "memory");  // next tile landed (issued a phase ago)
    bar();
  }

  // store unnormalized partials: row = q0 + i*16 + lg*4 + q, col = j*16 + lr
  size_t rbase = ((size_t)sp * HH + h) * LL;
#pragma unroll
  for (int i = 0; i < 2; ++i)
#pragma unroll
    for (int j = 0; j < 4; ++j)
#pragma unroll
      for (int q = 0; q < 4; ++q) {
        int row = q0 + i * 16 + lg * 4 + q;
        Op[(rbase + row) * 64 + j * 16 + lr] = o[i][j][q];
      }
  // rowsum: ol[i][q] identical across the 16 lr lanes; row = q0+i*16+lg*4+q
  if (lr == 0) {
#pragma unroll
    for (int i = 0; i < 2; ++i)
#pragma unroll
      for (int q = 0; q < 4; ++q)
        lb[rbase + q0 + i * 16 + lg * 4 + q] = ol[i][q];
  }
}

// ---------------- combine partials -> ctx bf16 [L][C] ----------------
__global__ __launch_bounds__(256) void k_comb(
    const float* __restrict__ Op, const float* __restrict__ lb,
    ushort* __restrict__ ctx) {
  int t = threadIdx.x;
  int h = blockIdx.y;
  int row = blockIdx.x * 64 + (t >> 2);
  int d0 = (t & 3) * 16;

  float Lsum = 0.f;
#pragma unroll
  for (int s = 0; s < SPLIT; ++s)
    Lsum += lb[((size_t)s * HH + h) * LL + row];
  float inv = 1.0f / Lsum;

  float acc[16] = {};
#pragma unroll
  for (int s = 0; s < SPLIT; ++s) {
    size_t rb = (((size_t)s * HH + h) * LL + row) * 64 + d0;
#pragma unroll
    for (int i = 0; i < 4; ++i) {
      float4 v = *(const float4*)(Op + rb + i * 4);
      acc[i * 4 + 0] += v.x;
      acc[i * 4 + 1] += v.y;
      acc[i * 4 + 2] += v.z;
      acc[i * 4 + 3] += v.w;
    }
  }
  ushort ob[16];
#pragma unroll
  for (int i = 0; i < 16; ++i) ob[i] = f2bf(acc[i] * inv);
  ushort* dst = ctx + (size_t)row * CC + h * 64 + d0;
  *(uint4*)(dst + 0) = *(uint4*)(ob + 0);
  *(uint4*)(dst + 8) = *(uint4*)(ob + 8);
}

extern "C" void kernel_launch(void* const* d_in, const int* in_sizes, int n_in,
                              void* d_out, int out_size, void* d_ws, size_t ws_size,
                              hipStream_t stream) {
  const float* hs  = (const float*)d_in[0];
  const float* Kbg = (const float*)d_in[1];
  const float* Vbg = (const float*)d_in[2];
  const float* Wq  = (const float*)d_in[3];
  const float* Wk  = (const float*)d_in[4];
  const float* Wv  = (const float*)d_in[5];
  const float* Wo  = (const float*)d_in[6];
  const float* bo  = (const float*)d_in[7];
  float* out = (float*)d_out;

  char* p = (char*)d_ws;
  ushort* hs_b = (ushort*)p; p += (size_t)LL * CC * 2;
  ushort* WqT  = (ushort*)p; p += (size_t)CC * CC * 2;
  ushort* WkT  = (ushort*)p; p += (size_t)CC * CC * 2;
  ushort* WvT  = (ushort*)p; p += (size_t)CC * CC * 2;
  ushort* WoT  = (ushort*)p; p += (size_t)CC * CC * 2;
  ushort* qb   = (ushort*)p; p += (size_t)HH * LL * DD * 2;
  ushort* kb   = (ushort*)p; p += (size_t)HH * KVL * DD * 2;
  ushort* vbT  = (ushort*)p; p += (size_t)HH * KVL * DD * 2;
  ushort* ctxb = (ushort*)p; p += (size_t)LL * CC * 2;
  float* Opart = (float*)p;  p += (size_t)SPLIT * HH * LL * DD * 4;
  float* lb    = (float*)p;  p += (size_t)SPLIT * HH * LL * 4;

  int n4hs = LL * CC / 4;
  k_cvt_hs<<<(n4hs + 255) / 256, 256, 0, stream>>>(hs, hs_b, n4hs);
  k_wT<<<dim3(CC / 64, CC / 64), 256, 0, stream>>>(Wq, WqT);
  k_wT<<<dim3(CC / 64, CC / 64), 256, 0, stream>>>(Wk, WkT);
  k_wT<<<dim3(CC / 64, CC / 64), 256, 0, stream>>>(Wv, WvT);
  k_wT<<<dim3(CC / 64, CC / 64), 256, 0, stream>>>(Wo, WoT);
  int n4bg = HH * LL * DD / 4;
  k_cvt_bg<<<(n4bg + 255) / 256, 256, 0, stream>>>(Kbg, Vbg, kb, vbT, n4bg);

  k_gemm<0><<<dim3(LL / 128, CC / 64), 512, 0, stream>>>(
      hs_b, WqT, qb, nullptr, nullptr, LL, CC, CC, (size_t)LL * DD);
  k_gemm<1><<<dim3(LL / 128, CC / 64), 512, 0, stream>>>(
      hs_b, WkT, kb, nullptr, nullptr, LL, CC, CC, (size_t)KVL * DD);
  k_gemm<2><<<dim3(LL / 128, CC / 64), 512, 0, stream>>>(
      hs_b, WvT, vbT, nullptr, nullptr, LL, CC, CC, 0);

  k_attn<<<dim3(16 * HH * SPLIT), 512, 0, stream>>>(qb, kb, vbT, Opart, lb);
  k_comb<<<dim3(LL / 64, HH), 256, 0, stream>>>(Opart, lb, ctxb);

  k_gemm<3><<<dim3(LL / 128, CC / 64), 512, 0, stream>>>(
      ctxb, WoT, nullptr, out, bo, LL, CC, CC, 0);
}

// Round 8
// 196.570 us; speedup vs baseline: 1.1059x; 1.1059x over previous
//
#include <hip/hip_runtime.h>
#include <stdint.h>

#define HH 10
#define DD 64
#define LL 4096
#define CC 640
#define KVL 8192
#define ALPHA 0.42f
#define SPLIT 4
#define SC2 0.1803368801111204f  // (1/sqrt(64)) * log2(e)

typedef __attribute__((ext_vector_type(8))) short s16x8;
typedef __attribute__((ext_vector_type(4))) float f32x4;

__device__ inline ushort f2bf(float f) {
  uint32_t u = __builtin_bit_cast(uint32_t, f);
  u += 0x7FFFu + ((u >> 16) & 1u);   // RNE
  return (ushort)(u >> 16);
}

__device__ inline uint cvtpk(float lo, float hi) {
  uint r;
  asm("v_cvt_pk_bf16_f32 %0, %1, %2" : "=v"(r) : "v"(lo), "v"(hi));
  return r;
}

__device__ inline void gl16(const ushort* g, ushort* l) {
  __builtin_amdgcn_global_load_lds(
      (const __attribute__((address_space(1))) uint32_t*)g,
      (__attribute__((address_space(3))) uint32_t*)l, 16, 0, 0);
}

__device__ inline void bar() {
  __builtin_amdgcn_sched_barrier(0);
  __builtin_amdgcn_s_barrier();
  __builtin_amdgcn_sched_barrier(0);
}

// V^T tile column position for kv-local row kl (0..63), matching the
// register layout of the swapped-QK^T P fragment (see k_attn):
// A-slot s=8*lg+m (within 32-block k0) must hold kv = 32*k0+16*(m>>2)+4*lg+(m&3).
// Inverse: p = (kl&32) | ((kl&12)<<1) | ((kl&16)>>2) | (kl&3)
__device__ inline int vpos(int kl) {
  return (kl & 32) | ((kl & 12) << 1) | ((kl & 16) >> 2) | (kl & 3);
}

// ---------------- prep: hs fp32 -> bf16 ----------------
__global__ void k_cvt_hs(const float* __restrict__ in, ushort* __restrict__ out, int n4) {
  int i = blockIdx.x * blockDim.x + threadIdx.x;
  if (i < n4) {
    float4 v = ((const float4*)in)[i];
    ushort4 o;
    o.x = f2bf(v.x); o.y = f2bf(v.y); o.z = f2bf(v.z); o.w = f2bf(v.w);
    ((ushort4*)out)[i] = o;
  }
}

// ---------------- prep: W [K][N] fp32 -> WT [N][K] bf16 ----------------
__global__ void k_wT(const float* __restrict__ W, ushort* __restrict__ WT) {
  __shared__ ushort t[64][65];
  int k0 = blockIdx.x * 64, n0 = blockIdx.y * 64;
  int tid = threadIdx.x;
#pragma unroll
  for (int i = 0; i < 4; ++i) {
    int id = tid + i * 256;
    int r = id >> 4, c4 = id & 15;
    float4 v = *(const float4*)(W + (size_t)(k0 + r) * CC + n0 + c4 * 4);
    t[r][c4 * 4 + 0] = f2bf(v.x);
    t[r][c4 * 4 + 1] = f2bf(v.y);
    t[r][c4 * 4 + 2] = f2bf(v.z);
    t[r][c4 * 4 + 3] = f2bf(v.w);
  }
  __syncthreads();
#pragma unroll
  for (int i = 0; i < 2; ++i) {
    int id = tid + i * 256;
    int n = id >> 3, cc = id & 7;
    ushort tmp[8];
#pragma unroll
    for (int j = 0; j < 8; ++j) tmp[j] = t[cc * 8 + j][n];
    *(uint4*)(WT + (size_t)(n0 + n) * CC + k0 + cc * 8) = *(uint4*)tmp;
  }
}

// ---------------- prep: background KV (rows L..KVL-1) ----------------
__global__ void k_cvt_bg(const float* __restrict__ Kbg, const float* __restrict__ Vbg,
                         ushort* __restrict__ kb, ushort* __restrict__ vbT, int n4) {
  int i = blockIdx.x * blockDim.x + threadIdx.x;
  if (i >= n4) return;
  int e = i * 4;
  int h = e / (LL * DD);
  int rem = e - h * (LL * DD);
  int kvl = rem >> 6;        // local row 0..4095
  int d0 = rem & 63;         // multiple of 4
  int kv = LL + kvl;         // global kv row
  float4 kf = ((const float4*)Kbg)[i];
  float4 vf = ((const float4*)Vbg)[i];
  {  // K: row-swizzled 16B chunks
    int chunk = d0 >> 3, off = d0 & 7;
    size_t kdst = ((size_t)h * KVL + kv) * 64 + (size_t)(((chunk ^ (kv & 7)) << 3) + off);
    ushort4 ok;
    ok.x = f2bf(ALPHA * kf.x); ok.y = f2bf(ALPHA * kf.y);
    ok.z = f2bf(ALPHA * kf.z); ok.w = f2bf(ALPHA * kf.w);
    *(ushort4*)(kb + kdst) = ok;
  }
  {  // V^T tiles: position-permuted + swizzled
    int tile = kv >> 6, kl = kv & 63;
    int c = vpos(kl);
    size_t vbase = ((size_t)h * 128 + tile) * 4096;
    float vv[4] = {vf.x, vf.y, vf.z, vf.w};
#pragma unroll
    for (int j = 0; j < 4; ++j) {
      int d = d0 + j;
      vbT[vbase + d * 64 + (((c >> 3) ^ (d & 7)) << 3) + (c & 7)] = f2bf(ALPHA * vv[j]);
    }
  }
}

// ---------------- bf16 GEMM: C[M][N] = A[M][K] * BT[N][K]^T ----------------
// MODE 0: Q head layout, scaled by SC2  MODE 1: K row-swizzled
// MODE 2: V^T permuted tiles            MODE 3: fp32 + bias (final)
template <int MODE>
__global__ __launch_bounds__(512) void k_gemm(
    const ushort* __restrict__ A, const ushort* __restrict__ BT,
    ushort* __restrict__ outB, float* __restrict__ outF,
    const float* __restrict__ bias, int M, int Kd, int N, size_t headStride) {
  __shared__ uint4 As4[128 * 8];
  __shared__ uint4 Bs4[64 * 8];
  int tid = threadIdx.x;
  int m0 = blockIdx.x * 128, n0 = blockIdx.y * 64;
  int wid = tid >> 6, lane = tid & 63;
  int wr = wid >> 1, wc = wid & 1;
  int lr = lane & 15, lg = lane >> 4;
  f32x4 acc[2][2] = {};

  for (int kt = 0; kt < Kd; kt += 64) {
    __syncthreads();
    {
      int id = tid;
#pragma unroll
      for (int i = 0; i < 2; ++i, id += 512) {
        int r = id >> 3, cc = id & 7;
        uint4 v = *(const uint4*)(A + (size_t)(m0 + r) * Kd + kt + cc * 8);
        As4[r * 8 + (cc ^ (r & 7))] = v;
      }
      int r = tid >> 3, cc = tid & 7;
      uint4 v = *(const uint4*)(BT + (size_t)(n0 + r) * Kd + kt + cc * 8);
      Bs4[r * 8 + (cc ^ (r & 7))] = v;
    }
    __syncthreads();
#pragma unroll
    for (int k0 = 0; k0 < 2; ++k0) {
      s16x8 a[2], b[2];
#pragma unroll
      for (int i = 0; i < 2; ++i) {
        int r = wr * 32 + i * 16 + lr;
        a[i] = *(const s16x8*)&As4[r * 8 + ((k0 * 4 + lg) ^ (r & 7))];
      }
#pragma unroll
      for (int j = 0; j < 2; ++j) {
        int r = wc * 32 + j * 16 + lr;
        b[j] = *(const s16x8*)&Bs4[r * 8 + ((k0 * 4 + lg) ^ (r & 7))];
      }
#pragma unroll
      for (int i = 0; i < 2; ++i)
#pragma unroll
        for (int j = 0; j < 2; ++j)
          acc[i][j] = __builtin_amdgcn_mfma_f32_16x16x32_bf16(a[i], b[j], acc[i][j], 0, 0, 0);
    }
  }
#pragma unroll
  for (int i = 0; i < 2; ++i)
#pragma unroll
    for (int j = 0; j < 2; ++j)
#pragma unroll
      for (int q = 0; q < 4; ++q) {
        int m = m0 + wr * 32 + i * 16 + lg * 4 + q;
        int n = n0 + wc * 32 + j * 16 + lr;
        float v = acc[i][j][q];
        if (MODE == 3) {
          outF[(size_t)m * N + n] = v + bias[n];
        } else if (MODE == 0) {
          outB[(size_t)(n >> 6) * headStride + (size_t)m * 64 + (n & 63)] = f2bf(v * SC2);
        } else if (MODE == 1) {
          int d = n & 63;
          outB[(size_t)(n >> 6) * headStride + (size_t)m * 64 +
               (((d >> 3) ^ (m & 7)) << 3) + (d & 7)] = f2bf(v);
        } else {  // MODE 2: V^T tiles, permuted positions
          int d = n & 63, tile = m >> 6, kl = m & 63;
          int c = vpos(kl);
          outB[((size_t)(n >> 6) * 128 + tile) * 4096 + (size_t)d * 64 +
               (((c >> 3) ^ (d & 7)) << 3) + (c & 7)] = f2bf(v);
        }
      }
}

// ---------------- flash attention (KV-split, static max, in-register P) ----------------
// grid 1280 flat = 8 XCDs x 160; remapped so each XCD serves a contiguous
// logical span (5 KV slices = 2.5MB -> fits 4MB XCD L2).
// 256 threads = 4 waves, wave owns 32 q-rows (block covers 128), KVBLK=64.
// Swapped QK^T keeps P in registers; rowsum via ones-MFMA on the matrix pipe.
__global__ __launch_bounds__(256, 4) void k_attn(
    const ushort* __restrict__ qb,    // [H][L][64], pre-scaled by SC2
    const ushort* __restrict__ kb,    // [H][KVL][64] row-swizzled
    const ushort* __restrict__ vbT,   // [H][128][4096] V^T permuted tiles
    float* __restrict__ Op,           // [SPLIT][H][L][64] unnormalized
    float* __restrict__ lb) {         // [SPLIT][H][L] row sums
  __shared__ ushort Ks[2][4096];
  __shared__ ushort Vs[2][4096];

  int tid = threadIdx.x, wid = tid >> 6, lane = tid & 63;
  int lr = lane & 15, lg = lane >> 4;

  // XCD-contiguous remap: dispatch round-robins flat%8 across XCDs; give each
  // XCD a contiguous logical span of 160 blocks (32 qblk x 5 (h,sp) pairs).
  int flat = blockIdx.x;
  int f2 = (flat & 7) * 160 + (flat >> 3);
  int qblk = f2 & 31;
  int hs = f2 >> 5;          // 0..39
  int h = hs % HH;
  int sp = hs / HH;
  int q0 = qblk * 128 + wid * 32;

  // Q fragments: 2 row-blocks x 2 k-chunks (B-operand layout: lane -> Q[row=lr][d=lg*8..])
  s16x8 qa[2][2];
#pragma unroll
  for (int i = 0; i < 2; ++i) {
    const ushort* qptr = qb + ((size_t)h * LL + q0 + i * 16 + lr) * DD + lg * 8;
    qa[i][0] = *(const s16x8*)qptr;
    qa[i][1] = *(const s16x8*)(qptr + 32);
  }

  // ones B-fragment for rowsum MFMA
  s16x8 ones;
#pragma unroll
  for (int i = 0; i < 8; ++i) ones[i] = (short)0x3F80;

  f32x4 o[2][4] = {};
  f32x4 ol[2] = {};

  const int t0 = sp * (KVL / SPLIT / 64), NT = KVL / SPLIT / 64;
  const ushort* kh = kb + (size_t)h * KVL * DD + (size_t)t0 * 4096;
  const ushort* vh = vbT + (size_t)h * 128 * 4096 + (size_t)t0 * 4096;

  // prologue: stage tile 0 (2 K + 2 V gl16 per thread), wait, sync
#pragma unroll
  for (int i = 0; i < 2; ++i) {
    gl16(kh + (i * 256 + tid) * 8, &Ks[0][i * 2048 + wid * 512]);
    gl16(vh + (i * 256 + tid) * 8, &Vs[0][i * 2048 + wid * 512]);
  }
  asm volatile("s_waitcnt vmcnt(0)" ::: "memory");
  bar();

  for (int t = 0; t < NT; ++t) {
    if (t < NT - 1) {
      int nb = (t + 1) & 1;
      const ushort* gk = kh + (size_t)(t + 1) * 4096;
      const ushort* gv = vh + (size_t)(t + 1) * 4096;
#pragma unroll
      for (int i = 0; i < 2; ++i) {
        gl16(gk + (i * 256 + tid) * 8, &Ks[nb][i * 2048 + wid * 512]);
        gl16(gv + (i * 256 + tid) * 8, &Vs[nb][i * 2048 + wid * 512]);
      }
    }

    const ushort* Kc = Ks[t & 1];
    const ushort* Vc = Vs[t & 1];

    // S^T = K Q^T : 16 MFMA. Lane (lg,lr), reg r of s[i][j]:
    //   S[q = q0+i*16+lr][kv = t*64 + j*16 + lg*4 + r]
    f32x4 s[2][4] = {};
    __builtin_amdgcn_s_setprio(1);
#pragma unroll
    for (int k0 = 0; k0 < 2; ++k0) {
#pragma unroll
      for (int j = 0; j < 4; ++j) {
        int r = j * 16 + lr;
        s16x8 kf = *(const s16x8*)&Kc[r * 64 + (((k0 * 4 + lg) ^ (r & 7)) << 3)];
        s[0][j] = __builtin_amdgcn_mfma_f32_16x16x32_bf16(kf, qa[0][k0], s[0][j], 0, 0, 0);
        s[1][j] = __builtin_amdgcn_mfma_f32_16x16x32_bf16(kf, qa[1][k0], s[1][j], 0, 0, 0);
      }
    }
    __builtin_amdgcn_s_setprio(0);

    // P = exp2(S) (Q pre-scaled, static max), pack to bf16 pairs in-register
    uint w[2][4][2];
#pragma unroll
    for (int i = 0; i < 2; ++i) {
#pragma unroll
      for (int j = 0; j < 4; ++j)
#pragma unroll
        for (int q = 0; q < 4; ++q)
          s[i][j][q] = exp2f(s[i][j][q]);
#pragma unroll
      for (int j = 0; j < 4; ++j) {
        w[i][j][0] = cvtpk(s[i][j][0], s[i][j][1]);
        w[i][j][1] = cvtpk(s[i][j][2], s[i][j][3]);
      }
    }

    // O += P V (16 MFMA) and rowsum l += P·1 (4 MFMA, matrix pipe)
    __builtin_amdgcn_s_setprio(1);
#pragma unroll
    for (int k0 = 0; k0 < 2; ++k0) {
      uint4 u0, u1;
      u0.x = w[0][2 * k0][0]; u0.y = w[0][2 * k0][1];
      u0.z = w[0][2 * k0 + 1][0]; u0.w = w[0][2 * k0 + 1][1];
      u1.x = w[1][2 * k0][0]; u1.y = w[1][2 * k0][1];
      u1.z = w[1][2 * k0 + 1][0]; u1.w = w[1][2 * k0 + 1][1];
      s16x8 pa0 = __builtin_bit_cast(s16x8, u0);
      s16x8 pa1 = __builtin_bit_cast(s16x8, u1);
      ol[0] = __builtin_amdgcn_mfma_f32_16x16x32_bf16(pa0, ones, ol[0], 0, 0, 0);
      ol[1] = __builtin_amdgcn_mfma_f32_16x16x32_bf16(pa1, ones, ol[1], 0, 0, 0);
#pragma unroll
      for (int j = 0; j < 4; ++j) {
        int r = j * 16 + lr;  // d row in V^T
        s16x8 bv = *(const s16x8*)&Vc[r * 64 + (((k0 * 4 + lg) ^ (r & 7)) << 3)];
        o[0][j] = __builtin_amdgcn_mfma_f32_16x16x32_bf16(pa0, bv, o[0][j], 0, 0, 0);
        o[1][j] = __builtin_amdgcn_mfma_f32_16x16x32_bf16(pa1, bv, o[1][j], 0, 0, 0);
      }
    }
    __builtin_amdgcn_s_setprio(0);

    asm volatile("s_waitcnt vmcnt(0)" ::: "memory");  // next tile landed (issued a phase ago)
    bar();
  }

  // store unnormalized partials: row = q0 + i*16 + lg*4 + q, col = j*16 + lr
  size_t rbase = ((size_t)sp * HH + h) * LL;
#pragma unroll
  for (int i = 0; i < 2; ++i)
#pragma unroll
    for (int j = 0; j < 4; ++j)
#pragma unroll
      for (int q = 0; q < 4; ++q) {
        int row = q0 + i * 16 + lg * 4 + q;
        Op[(rbase + row) * 64 + j * 16 + lr] = o[i][j][q];
      }
  // rowsum: ol[i][q] identical across the 16 lr lanes; row = q0+i*16+lg*4+q
  if (lr == 0) {
#pragma unroll
    for (int i = 0; i < 2; ++i)
#pragma unroll
      for (int q = 0; q < 4; ++q)
        lb[rbase + q0 + i * 16 + lg * 4 + q] = ol[i][q];
  }
}

// ---------------- combine partials -> ctx bf16 [L][C] ----------------
__global__ __launch_bounds__(256) void k_comb(
    const float* __restrict__ Op, const float* __restrict__ lb,
    ushort* __restrict__ ctx) {
  int t = threadIdx.x;
  int h = blockIdx.y;
  int row = blockIdx.x * 64 + (t >> 2);
  int d0 = (t & 3) * 16;

  float Lsum = 0.f;
#pragma unroll
  for (int s = 0; s < SPLIT; ++s)
    Lsum += lb[((size_t)s * HH + h) * LL + row];
  float inv = 1.0f / Lsum;

  float acc[16] = {};
#pragma unroll
  for (int s = 0; s < SPLIT; ++s) {
    size_t rb = (((size_t)s * HH + h) * LL + row) * 64 + d0;
#pragma unroll
    for (int i = 0; i < 4; ++i) {
      float4 v = *(const float4*)(Op + rb + i * 4);
      acc[i * 4 + 0] += v.x;
      acc[i * 4 + 1] += v.y;
      acc[i * 4 + 2] += v.z;
      acc[i * 4 + 3] += v.w;
    }
  }
  ushort ob[16];
#pragma unroll
  for (int i = 0; i < 16; ++i) ob[i] = f2bf(acc[i] * inv);
  ushort* dst = ctx + (size_t)row * CC + h * 64 + d0;
  *(uint4*)(dst + 0) = *(uint4*)(ob + 0);
  *(uint4*)(dst + 8) = *(uint4*)(ob + 8);
}

extern "C" void kernel_launch(void* const* d_in, const int* in_sizes, int n_in,
                              void* d_out, int out_size, void* d_ws, size_t ws_size,
                              hipStream_t stream) {
  const float* hs  = (const float*)d_in[0];
  const float* Kbg = (const float*)d_in[1];
  const float* Vbg = (const float*)d_in[2];
  const float* Wq  = (const float*)d_in[3];
  const float* Wk  = (const float*)d_in[4];
  const float* Wv  = (const float*)d_in[5];
  const float* Wo  = (const float*)d_in[6];
  const float* bo  = (const float*)d_in[7];
  float* out = (float*)d_out;

  char* p = (char*)d_ws;
  ushort* hs_b = (ushort*)p; p += (size_t)LL * CC * 2;
  ushort* WqT  = (ushort*)p; p += (size_t)CC * CC * 2;
  ushort* WkT  = (ushort*)p; p += (size_t)CC * CC * 2;
  ushort* WvT  = (ushort*)p; p += (size_t)CC * CC * 2;
  ushort* WoT  = (ushort*)p; p += (size_t)CC * CC * 2;
  ushort* qb   = (ushort*)p; p += (size_t)HH * LL * DD * 2;
  ushort* kb   = (ushort*)p; p += (size_t)HH * KVL * DD * 2;
  ushort* vbT  = (ushort*)p; p += (size_t)HH * KVL * DD * 2;
  ushort* ctxb = (ushort*)p; p += (size_t)LL * CC * 2;
  float* Opart = (float*)p;  p += (size_t)SPLIT * HH * LL * DD * 4;
  float* lb    = (float*)p;  p += (size_t)SPLIT * HH * LL * 4;

  int n4hs = LL * CC / 4;
  k_cvt_hs<<<(n4hs + 255) / 256, 256, 0, stream>>>(hs, hs_b, n4hs);
  k_wT<<<dim3(CC / 64, CC / 64), 256, 0, stream>>>(Wq, WqT);
  k_wT<<<dim3(CC / 64, CC / 64), 256, 0, stream>>>(Wk, WkT);
  k_wT<<<dim3(CC / 64, CC / 64), 256, 0, stream>>>(Wv, WvT);
  k_wT<<<dim3(CC / 64, CC / 64), 256, 0, stream>>>(Wo, WoT);
  int n4bg = HH * LL * DD / 4;
  k_cvt_bg<<<(n4bg + 255) / 256, 256, 0, stream>>>(Kbg, Vbg, kb, vbT, n4bg);

  k_gemm<0><<<dim3(LL / 128, CC / 64), 512, 0, stream>>>(
      hs_b, WqT, qb, nullptr, nullptr, LL, CC, CC, (size_t)LL * DD);
  k_gemm<1><<<dim3(LL / 128, CC / 64), 512, 0, stream>>>(
      hs_b, WkT, kb, nullptr, nullptr, LL, CC, CC, (size_t)KVL * DD);
  k_gemm<2><<<dim3(LL / 128, CC / 64), 512, 0, stream>>>(
      hs_b, WvT, vbT, nullptr, nullptr, LL, CC, CC, 0);

  k_attn<<<dim3(32 * HH * SPLIT), 256, 0, stream>>>(qb, kb, vbT, Opart, lb);
  k_comb<<<dim3(LL / 64, HH), 256, 0, stream>>>(Opart, lb, ctxb);

  k_gemm<3><<<dim3(LL / 128, CC / 64), 512, 0, stream>>>(
      ctxb, WoT, nullptr, out, bo, LL, CC, CC, 0);
}

// Round 9
// 182.582 us; speedup vs baseline: 1.1906x; 1.0766x over previous
//
#include <hip/hip_runtime.h>
#include <stdint.h>

#define HH 10
#define DD 64
#define LL 4096
#define CC 640
#define KVL 8192
#define ALPHA 0.42f
#define SPLIT 4
#define SC2 0.1803368801111204f  // (1/sqrt(64)) * log2(e)

typedef __attribute__((ext_vector_type(8))) short s16x8;
typedef __attribute__((ext_vector_type(4))) float f32x4;

__device__ inline ushort f2bf(float f) {
  uint32_t u = __builtin_bit_cast(uint32_t, f);
  u += 0x7FFFu + ((u >> 16) & 1u);   // RNE
  return (ushort)(u >> 16);
}

__device__ inline uint cvtpk(float lo, float hi) {
  uint r;
  asm("v_cvt_pk_bf16_f32 %0, %1, %2" : "=v"(r) : "v"(lo), "v"(hi));
  return r;
}

__device__ inline float fexp2(float x) {
  float r;
  asm("v_exp_f32 %0, %1" : "=v"(r) : "v"(x));  // pure, schedulable
  return r;
}

__device__ inline void gl16(const ushort* g, ushort* l) {
  __builtin_amdgcn_global_load_lds(
      (const __attribute__((address_space(1))) uint32_t*)g,
      (__attribute__((address_space(3))) uint32_t*)l, 16, 0, 0);
}

__device__ inline void bar() {
  __builtin_amdgcn_sched_barrier(0);
  __builtin_amdgcn_s_barrier();
  __builtin_amdgcn_sched_barrier(0);
}

// V^T tile column position for kv-local row kl (0..63), matching the
// register layout of the swapped-QK^T P fragment (see k_attn):
// A-slot s=8*lg+m (within 32-block k0) must hold kv = 32*k0+16*(m>>2)+4*lg+(m&3).
// Inverse: p = (kl&32) | ((kl&12)<<1) | ((kl&16)>>2) | (kl&3)
__device__ inline int vpos(int kl) {
  return (kl & 32) | ((kl & 12) << 1) | ((kl & 16) >> 2) | (kl & 3);
}

// ---------------- prep: hs fp32 -> bf16 ----------------
__global__ void k_cvt_hs(const float* __restrict__ in, ushort* __restrict__ out, int n4) {
  int i = blockIdx.x * blockDim.x + threadIdx.x;
  if (i < n4) {
    float4 v = ((const float4*)in)[i];
    ushort4 o;
    o.x = f2bf(v.x); o.y = f2bf(v.y); o.z = f2bf(v.z); o.w = f2bf(v.w);
    ((ushort4*)out)[i] = o;
  }
}

// ---------------- prep: W [K][N] fp32 -> WT [N][K] bf16 ----------------
__global__ void k_wT(const float* __restrict__ W, ushort* __restrict__ WT) {
  __shared__ ushort t[64][65];
  int k0 = blockIdx.x * 64, n0 = blockIdx.y * 64;
  int tid = threadIdx.x;
#pragma unroll
  for (int i = 0; i < 4; ++i) {
    int id = tid + i * 256;
    int r = id >> 4, c4 = id & 15;
    float4 v = *(const float4*)(W + (size_t)(k0 + r) * CC + n0 + c4 * 4);
    t[r][c4 * 4 + 0] = f2bf(v.x);
    t[r][c4 * 4 + 1] = f2bf(v.y);
    t[r][c4 * 4 + 2] = f2bf(v.z);
    t[r][c4 * 4 + 3] = f2bf(v.w);
  }
  __syncthreads();
#pragma unroll
  for (int i = 0; i < 2; ++i) {
    int id = tid + i * 256;
    int n = id >> 3, cc = id & 7;
    ushort tmp[8];
#pragma unroll
    for (int j = 0; j < 8; ++j) tmp[j] = t[cc * 8 + j][n];
    *(uint4*)(WT + (size_t)(n0 + n) * CC + k0 + cc * 8) = *(uint4*)tmp;
  }
}

// ---------------- prep: background KV (rows L..KVL-1) ----------------
__global__ void k_cvt_bg(const float* __restrict__ Kbg, const float* __restrict__ Vbg,
                         ushort* __restrict__ kb, ushort* __restrict__ vbT, int n4) {
  int i = blockIdx.x * blockDim.x + threadIdx.x;
  if (i >= n4) return;
  int e = i * 4;
  int h = e / (LL * DD);
  int rem = e - h * (LL * DD);
  int kvl = rem >> 6;        // local row 0..4095
  int d0 = rem & 63;         // multiple of 4
  int kv = LL + kvl;         // global kv row
  float4 kf = ((const float4*)Kbg)[i];
  float4 vf = ((const float4*)Vbg)[i];
  {  // K: row-swizzled 16B chunks
    int chunk = d0 >> 3, off = d0 & 7;
    size_t kdst = ((size_t)h * KVL + kv) * 64 + (size_t)(((chunk ^ (kv & 7)) << 3) + off);
    ushort4 ok;
    ok.x = f2bf(ALPHA * kf.x); ok.y = f2bf(ALPHA * kf.y);
    ok.z = f2bf(ALPHA * kf.z); ok.w = f2bf(ALPHA * kf.w);
    *(ushort4*)(kb + kdst) = ok;
  }
  {  // V^T tiles: position-permuted + swizzled
    int tile = kv >> 6, kl = kv & 63;
    int c = vpos(kl);
    size_t vbase = ((size_t)h * 128 + tile) * 4096;
    float vv[4] = {vf.x, vf.y, vf.z, vf.w};
#pragma unroll
    for (int j = 0; j < 4; ++j) {
      int d = d0 + j;
      vbT[vbase + d * 64 + (((c >> 3) ^ (d & 7)) << 3) + (c & 7)] = f2bf(ALPHA * vv[j]);
    }
  }
}

// ---------------- bf16 GEMM: C[M][N] = A[M][K] * BT[N][K]^T ----------------
// MODE 0: Q head layout, scaled by SC2  MODE 1: K row-swizzled
// MODE 2: V^T permuted tiles            MODE 3: fp32 + bias (final)
template <int MODE>
__global__ __launch_bounds__(512) void k_gemm(
    const ushort* __restrict__ A, const ushort* __restrict__ BT,
    ushort* __restrict__ outB, float* __restrict__ outF,
    const float* __restrict__ bias, int M, int Kd, int N, size_t headStride) {
  __shared__ uint4 As4[128 * 8];
  __shared__ uint4 Bs4[64 * 8];
  int tid = threadIdx.x;
  int m0 = blockIdx.x * 128, n0 = blockIdx.y * 64;
  int wid = tid >> 6, lane = tid & 63;
  int wr = wid >> 1, wc = wid & 1;
  int lr = lane & 15, lg = lane >> 4;
  f32x4 acc[2][2] = {};

  for (int kt = 0; kt < Kd; kt += 64) {
    __syncthreads();
    {
      int id = tid;
#pragma unroll
      for (int i = 0; i < 2; ++i, id += 512) {
        int r = id >> 3, cc = id & 7;
        uint4 v = *(const uint4*)(A + (size_t)(m0 + r) * Kd + kt + cc * 8);
        As4[r * 8 + (cc ^ (r & 7))] = v;
      }
      int r = tid >> 3, cc = tid & 7;
      uint4 v = *(const uint4*)(BT + (size_t)(n0 + r) * Kd + kt + cc * 8);
      Bs4[r * 8 + (cc ^ (r & 7))] = v;
    }
    __syncthreads();
#pragma unroll
    for (int k0 = 0; k0 < 2; ++k0) {
      s16x8 a[2], b[2];
#pragma unroll
      for (int i = 0; i < 2; ++i) {
        int r = wr * 32 + i * 16 + lr;
        a[i] = *(const s16x8*)&As4[r * 8 + ((k0 * 4 + lg) ^ (r & 7))];
      }
#pragma unroll
      for (int j = 0; j < 2; ++j) {
        int r = wc * 32 + j * 16 + lr;
        b[j] = *(const s16x8*)&Bs4[r * 8 + ((k0 * 4 + lg) ^ (r & 7))];
      }
#pragma unroll
      for (int i = 0; i < 2; ++i)
#pragma unroll
        for (int j = 0; j < 2; ++j)
          acc[i][j] = __builtin_amdgcn_mfma_f32_16x16x32_bf16(a[i], b[j], acc[i][j], 0, 0, 0);
    }
  }
#pragma unroll
  for (int i = 0; i < 2; ++i)
#pragma unroll
    for (int j = 0; j < 2; ++j)
#pragma unroll
      for (int q = 0; q < 4; ++q) {
        int m = m0 + wr * 32 + i * 16 + lg * 4 + q;
        int n = n0 + wc * 32 + j * 16 + lr;
        float v = acc[i][j][q];
        if (MODE == 3) {
          outF[(size_t)m * N + n] = v + bias[n];
        } else if (MODE == 0) {
          outB[(size_t)(n >> 6) * headStride + (size_t)m * 64 + (n & 63)] = f2bf(v * SC2);
        } else if (MODE == 1) {
          int d = n & 63;
          outB[(size_t)(n >> 6) * headStride + (size_t)m * 64 +
               (((d >> 3) ^ (m & 7)) << 3) + (d & 7)] = f2bf(v);
        } else {  // MODE 2: V^T tiles, permuted positions
          int d = n & 63, tile = m >> 6, kl = m & 63;
          int c = vpos(kl);
          outB[((size_t)(n >> 6) * 128 + tile) * 4096 + (size_t)d * 64 +
               (((c >> 3) ^ (d & 7)) << 3) + (c & 7)] = f2bf(v);
        }
      }
}

// ---------------- flash attention (KV-split, static max, in-register P) ----------------
// grid 640 flat = 8 XCDs x 80; remapped so each XCD serves a contiguous
// logical span (5 KV slices = 2.5MB -> fits 4MB XCD L2).
// 256 threads = 4 waves, wave owns 64 q-rows (4 row-blocks; block covers 256).
// K/V fragments loaded once per tile, reused across 4 row-blocks -> LDS
// traffic per output element halved vs 2-row-block version.
__global__ __launch_bounds__(256, 2) void k_attn(
    const ushort* __restrict__ qb,    // [H][L][64], pre-scaled by SC2
    const ushort* __restrict__ kb,    // [H][KVL][64] row-swizzled
    const ushort* __restrict__ vbT,   // [H][128][4096] V^T permuted tiles
    float* __restrict__ Op,           // [SPLIT][H][L][64] unnormalized
    float* __restrict__ lb) {         // [SPLIT][H][L] row sums
  __shared__ ushort Ks[2][4096];
  __shared__ ushort Vs[2][4096];

  int tid = threadIdx.x, wid = tid >> 6, lane = tid & 63;
  int lr = lane & 15, lg = lane >> 4;

  // XCD-contiguous remap: dispatch round-robins flat%8 across XCDs; give each
  // XCD a contiguous logical span of 80 blocks (16 qblk x 5 (h,sp) pairs).
  int flat = blockIdx.x;
  int f2 = (flat & 7) * 80 + (flat >> 3);
  int qblk = f2 & 15;
  int hs = f2 >> 4;          // 0..39
  int h = hs % HH;
  int sp = hs / HH;
  int q0 = qblk * 256 + wid * 64;

  // Q fragments: 4 row-blocks x 2 k-chunks (B-operand: lane -> Q[row=lr][d=lg*8..])
  s16x8 qa[4][2];
#pragma unroll
  for (int i = 0; i < 4; ++i) {
    const ushort* qptr = qb + ((size_t)h * LL + q0 + i * 16 + lr) * DD + lg * 8;
    qa[i][0] = *(const s16x8*)qptr;
    qa[i][1] = *(const s16x8*)(qptr + 32);
  }

  // ones B-fragment for rowsum MFMA
  s16x8 ones;
#pragma unroll
  for (int i = 0; i < 8; ++i) ones[i] = (short)0x3F80;

  f32x4 o[4][4] = {};
  f32x4 ol[4] = {};

  const int t0 = sp * (KVL / SPLIT / 64), NT = KVL / SPLIT / 64;
  const ushort* kh = kb + (size_t)h * KVL * DD + (size_t)t0 * 4096;
  const ushort* vh = vbT + (size_t)h * 128 * 4096 + (size_t)t0 * 4096;

  // prologue: stage tile 0 (2 K + 2 V gl16 per thread), wait, sync
#pragma unroll
  for (int i = 0; i < 2; ++i) {
    gl16(kh + (i * 256 + tid) * 8, &Ks[0][i * 2048 + wid * 512]);
    gl16(vh + (i * 256 + tid) * 8, &Vs[0][i * 2048 + wid * 512]);
  }
  asm volatile("s_waitcnt vmcnt(0)" ::: "memory");
  bar();

  for (int t = 0; t < NT; ++t) {
    if (t < NT - 1) {
      int nb = (t + 1) & 1;
      const ushort* gk = kh + (size_t)(t + 1) * 4096;
      const ushort* gv = vh + (size_t)(t + 1) * 4096;
#pragma unroll
      for (int i = 0; i < 2; ++i) {
        gl16(gk + (i * 256 + tid) * 8, &Ks[nb][i * 2048 + wid * 512]);
        gl16(gv + (i * 256 + tid) * 8, &Vs[nb][i * 2048 + wid * 512]);
      }
    }

    const ushort* Kc = Ks[t & 1];
    const ushort* Vc = Vs[t & 1];

    // S^T = K Q^T : 32 MFMA. Each K fragment feeds 4 row-block chains.
    // Lane (lg,lr), reg r of s[i][j]: S[q=q0+i*16+lr][kv=t*64+j*16+lg*4+r]
    f32x4 s[4][4] = {};
    __builtin_amdgcn_s_setprio(1);
#pragma unroll
    for (int k0 = 0; k0 < 2; ++k0) {
#pragma unroll
      for (int j = 0; j < 4; ++j) {
        int r = j * 16 + lr;
        s16x8 kf = *(const s16x8*)&Kc[r * 64 + (((k0 * 4 + lg) ^ (r & 7)) << 3)];
#pragma unroll
        for (int i = 0; i < 4; ++i)
          s[i][j] = __builtin_amdgcn_mfma_f32_16x16x32_bf16(kf, qa[i][k0], s[i][j], 0, 0, 0);
      }
    }
    __builtin_amdgcn_s_setprio(0);

    // P = exp2(S) (Q pre-scaled, static max), pack to bf16 pairs in-register
    uint w[4][4][2];
#pragma unroll
    for (int i = 0; i < 4; ++i)
#pragma unroll
      for (int j = 0; j < 4; ++j) {
        float p0 = fexp2(s[i][j][0]);
        float p1 = fexp2(s[i][j][1]);
        float p2 = fexp2(s[i][j][2]);
        float p3 = fexp2(s[i][j][3]);
        w[i][j][0] = cvtpk(p0, p1);
        w[i][j][1] = cvtpk(p2, p3);
      }

    // O += P V (32 MFMA) and rowsum l += P·1 (8 MFMA); V frag reused 4x
    __builtin_amdgcn_s_setprio(1);
#pragma unroll
    for (int k0 = 0; k0 < 2; ++k0) {
      s16x8 pa[4];
#pragma unroll
      for (int i = 0; i < 4; ++i) {
        uint4 u;
        u.x = w[i][2 * k0][0]; u.y = w[i][2 * k0][1];
        u.z = w[i][2 * k0 + 1][0]; u.w = w[i][2 * k0 + 1][1];
        pa[i] = __builtin_bit_cast(s16x8, u);
        ol[i] = __builtin_amdgcn_mfma_f32_16x16x32_bf16(pa[i], ones, ol[i], 0, 0, 0);
      }
#pragma unroll
      for (int j = 0; j < 4; ++j) {
        int r = j * 16 + lr;  // d row in V^T
        s16x8 bv = *(const s16x8*)&Vc[r * 64 + (((k0 * 4 + lg) ^ (r & 7)) << 3)];
#pragma unroll
        for (int i = 0; i < 4; ++i)
          o[i][j] = __builtin_amdgcn_mfma_f32_16x16x32_bf16(pa[i], bv, o[i][j], 0, 0, 0);
      }
    }
    __builtin_amdgcn_s_setprio(0);

    asm volatile("s_waitcnt vmcnt(0)" ::: "memory");  // next tile landed (issued a phase ago)
    bar();
  }

  // store unnormalized partials: row = q0 + i*16 + lg*4 + q, col = j*16 + lr
  size_t rbase = ((size_t)sp * HH + h) * LL;
#pragma unroll
  for (int i = 0; i < 4; ++i)
#pragma unroll
    for (int j = 0; j < 4; ++j)
#pragma unroll
      for (int q = 0; q < 4; ++q) {
        int row = q0 + i * 16 + lg * 4 + q;
        Op[(rbase + row) * 64 + j * 16 + lr] = o[i][j][q];
      }
  // rowsum: ol[i][q] identical across the 16 lr lanes; row = q0+i*16+lg*4+q
  if (lr == 0) {
#pragma unroll
    for (int i = 0; i < 4; ++i)
#pragma unroll
      for (int q = 0; q < 4; ++q)
        lb[rbase + q0 + i * 16 + lg * 4 + q] = ol[i][q];
  }
}

// ---------------- combine partials -> ctx bf16 [L][C] ----------------
__global__ __launch_bounds__(256) void k_comb(
    const float* __restrict__ Op, const float* __restrict__ lb,
    ushort* __restrict__ ctx) {
  int t = threadIdx.x;
  int h = blockIdx.y;
  int row = blockIdx.x * 64 + (t >> 2);
  int d0 = (t & 3) * 16;

  float Lsum = 0.f;
#pragma unroll
  for (int s = 0; s < SPLIT; ++s)
    Lsum += lb[((size_t)s * HH + h) * LL + row];
  float inv = 1.0f / Lsum;

  float acc[16] = {};
#pragma unroll
  for (int s = 0; s < SPLIT; ++s) {
    size_t rb = (((size_t)s * HH + h) * LL + row) * 64 + d0;
#pragma unroll
    for (int i = 0; i < 4; ++i) {
      float4 v = *(const float4*)(Op + rb + i * 4);
      acc[i * 4 + 0] += v.x;
      acc[i * 4 + 1] += v.y;
      acc[i * 4 + 2] += v.z;
      acc[i * 4 + 3] += v.w;
    }
  }
  ushort ob[16];
#pragma unroll
  for (int i = 0; i < 16; ++i) ob[i] = f2bf(acc[i] * inv);
  ushort* dst = ctx + (size_t)row * CC + h * 64 + d0;
  *(uint4*)(dst + 0) = *(uint4*)(ob + 0);
  *(uint4*)(dst + 8) = *(uint4*)(ob + 8);
}

extern "C" void kernel_launch(void* const* d_in, const int* in_sizes, int n_in,
                              void* d_out, int out_size, void* d_ws, size_t ws_size,
                              hipStream_t stream) {
  const float* hs  = (const float*)d_in[0];
  const float* Kbg = (const float*)d_in[1];
  const float* Vbg = (const float*)d_in[2];
  const float* Wq  = (const float*)d_in[3];
  const float* Wk  = (const float*)d_in[4];
  const float* Wv  = (const float*)d_in[5];
  const float* Wo  = (const float*)d_in[6];
  const float* bo  = (const float*)d_in[7];
  float* out = (float*)d_out;

  char* p = (char*)d_ws;
  ushort* hs_b = (ushort*)p; p += (size_t)LL * CC * 2;
  ushort* WqT  = (ushort*)p; p += (size_t)CC * CC * 2;
  ushort* WkT  = (ushort*)p; p += (size_t)CC * CC * 2;
  ushort* WvT  = (ushort*)p; p += (size_t)CC * CC * 2;
  ushort* WoT  = (ushort*)p; p += (size_t)CC * CC * 2;
  ushort* qb   = (ushort*)p; p += (size_t)HH * LL * DD * 2;
  ushort* kb   = (ushort*)p; p += (size_t)HH * KVL * DD * 2;
  ushort* vbT  = (ushort*)p; p += (size_t)HH * KVL * DD * 2;
  ushort* ctxb = (ushort*)p; p += (size_t)LL * CC * 2;
  float* Opart = (float*)p;  p += (size_t)SPLIT * HH * LL * DD * 4;
  float* lb    = (float*)p;  p += (size_t)SPLIT * HH * LL * 4;

  int n4hs = LL * CC / 4;
  k_cvt_hs<<<(n4hs + 255) / 256, 256, 0, stream>>>(hs, hs_b, n4hs);
  k_wT<<<dim3(CC / 64, CC / 64), 256, 0, stream>>>(Wq, WqT);
  k_wT<<<dim3(CC / 64, CC / 64), 256, 0, stream>>>(Wk, WkT);
  k_wT<<<dim3(CC / 64, CC / 64), 256, 0, stream>>>(Wv, WvT);
  k_wT<<<dim3(CC / 64, CC / 64), 256, 0, stream>>>(Wo, WoT);
  int n4bg = HH * LL * DD / 4;
  k_cvt_bg<<<(n4bg + 255) / 256, 256, 0, stream>>>(Kbg, Vbg, kb, vbT, n4bg);

  k_gemm<0><<<dim3(LL / 128, CC / 64), 512, 0, stream>>>(
      hs_b, WqT, qb, nullptr, nullptr, LL, CC, CC, (size_t)LL * DD);
  k_gemm<1><<<dim3(LL / 128, CC / 64), 512, 0, stream>>>(
      hs_b, WkT, kb, nullptr, nullptr, LL, CC, CC, (size_t)KVL * DD);
  k_gemm<2><<<dim3(LL / 128, CC / 64), 512, 0, stream>>>(
      hs_b, WvT, vbT, nullptr, nullptr, LL, CC, CC, 0);

  k_attn<<<dim3(16 * HH * SPLIT), 256, 0, stream>>>(qb, kb, vbT, Opart, lb);
  k_comb<<<dim3(LL / 64, HH), 256, 0, stream>>>(Opart, lb, ctxb);

  k_gemm<3><<<dim3(LL / 128, CC / 64), 512, 0, stream>>>(
      ctxb, WoT, nullptr, out, bo, LL, CC, CC, 0);
}

// Round 10
// 174.155 us; speedup vs baseline: 1.2482x; 1.0484x over previous
//
#include <hip/hip_runtime.h>
#include <stdint.h>

#define HH 10
#define DD 64
#define LL 4096
#define CC 640
#define KVL 8192
#define ALPHA 0.42f
#define SC2 0.1803368801111204f  // (1/sqrt(64)) * log2(e)

typedef __attribute__((ext_vector_type(8))) short s16x8;
typedef __attribute__((ext_vector_type(4))) float f32x4;

__device__ inline ushort f2bf(float f) {
  uint32_t u = __builtin_bit_cast(uint32_t, f);
  u += 0x7FFFu + ((u >> 16) & 1u);   // RNE
  return (ushort)(u >> 16);
}

__device__ inline uint cvtpk(float lo, float hi) {
  uint r;
  asm("v_cvt_pk_bf16_f32 %0, %1, %2" : "=v"(r) : "v"(lo), "v"(hi));
  return r;
}

__device__ inline float fexp2(float x) {
  float r;
  asm("v_exp_f32 %0, %1" : "=v"(r) : "v"(x));  // pure, schedulable
  return r;
}

__device__ inline void gl16(const ushort* g, ushort* l) {
  __builtin_amdgcn_global_load_lds(
      (const __attribute__((address_space(1))) uint32_t*)g,
      (__attribute__((address_space(3))) uint32_t*)l, 16, 0, 0);
}

__device__ inline void bar() {
  __builtin_amdgcn_sched_barrier(0);
  __builtin_amdgcn_s_barrier();
  __builtin_amdgcn_sched_barrier(0);
}

// V^T tile column position for kv-local row kl (0..63), matching the
// register layout of the swapped-QK^T P fragment (see k_attn):
// A-slot s=8*lg+m (within 32-block k0) must hold kv = 32*k0+16*(m>>2)+4*lg+(m&3).
// Inverse: p = (kl&32) | ((kl&12)<<1) | ((kl&16)>>2) | (kl&3)
__device__ inline int vpos(int kl) {
  return (kl & 32) | ((kl & 12) << 1) | ((kl & 16) >> 2) | (kl & 3);
}

// ---------------- prep: hs fp32 -> bf16 ----------------
__global__ void k_cvt_hs(const float* __restrict__ in, ushort* __restrict__ out, int n4) {
  int i = blockIdx.x * blockDim.x + threadIdx.x;
  if (i < n4) {
    float4 v = ((const float4*)in)[i];
    ushort4 o;
    o.x = f2bf(v.x); o.y = f2bf(v.y); o.z = f2bf(v.z); o.w = f2bf(v.w);
    ((ushort4*)out)[i] = o;
  }
}

// ---------------- prep: W [K][N] fp32 -> WT [N][K] bf16 ----------------
__global__ void k_wT(const float* __restrict__ W, ushort* __restrict__ WT) {
  __shared__ ushort t[64][65];
  int k0 = blockIdx.x * 64, n0 = blockIdx.y * 64;
  int tid = threadIdx.x;
#pragma unroll
  for (int i = 0; i < 4; ++i) {
    int id = tid + i * 256;
    int r = id >> 4, c4 = id & 15;
    float4 v = *(const float4*)(W + (size_t)(k0 + r) * CC + n0 + c4 * 4);
    t[r][c4 * 4 + 0] = f2bf(v.x);
    t[r][c4 * 4 + 1] = f2bf(v.y);
    t[r][c4 * 4 + 2] = f2bf(v.z);
    t[r][c4 * 4 + 3] = f2bf(v.w);
  }
  __syncthreads();
#pragma unroll
  for (int i = 0; i < 2; ++i) {
    int id = tid + i * 256;
    int n = id >> 3, cc = id & 7;
    ushort tmp[8];
#pragma unroll
    for (int j = 0; j < 8; ++j) tmp[j] = t[cc * 8 + j][n];
    *(uint4*)(WT + (size_t)(n0 + n) * CC + k0 + cc * 8) = *(uint4*)tmp;
  }
}

// ---------------- prep: background KV (rows L..KVL-1) ----------------
__global__ void k_cvt_bg(const float* __restrict__ Kbg, const float* __restrict__ Vbg,
                         ushort* __restrict__ kb, ushort* __restrict__ vbT, int n4) {
  int i = blockIdx.x * blockDim.x + threadIdx.x;
  if (i >= n4) return;
  int e = i * 4;
  int h = e / (LL * DD);
  int rem = e - h * (LL * DD);
  int kvl = rem >> 6;        // local row 0..4095
  int d0 = rem & 63;         // multiple of 4
  int kv = LL + kvl;         // global kv row
  float4 kf = ((const float4*)Kbg)[i];
  float4 vf = ((const float4*)Vbg)[i];
  {  // K: row-swizzled 16B chunks
    int chunk = d0 >> 3, off = d0 & 7;
    size_t kdst = ((size_t)h * KVL + kv) * 64 + (size_t)(((chunk ^ (kv & 7)) << 3) + off);
    ushort4 ok;
    ok.x = f2bf(ALPHA * kf.x); ok.y = f2bf(ALPHA * kf.y);
    ok.z = f2bf(ALPHA * kf.z); ok.w = f2bf(ALPHA * kf.w);
    *(ushort4*)(kb + kdst) = ok;
  }
  {  // V^T tiles: position-permuted + swizzled
    int tile = kv >> 6, kl = kv & 63;
    int c = vpos(kl);
    size_t vbase = ((size_t)h * 128 + tile) * 4096;
    float vv[4] = {vf.x, vf.y, vf.z, vf.w};
#pragma unroll
    for (int j = 0; j < 4; ++j) {
      int d = d0 + j;
      vbT[vbase + d * 64 + (((c >> 3) ^ (d & 7)) << 3) + (c & 7)] = f2bf(ALPHA * vv[j]);
    }
  }
}

// ---------------- bf16 GEMM: C[M][N] = A[M][K] * BT[N][K]^T ----------------
// MODE 0: Q head layout, scaled by SC2  MODE 1: K row-swizzled
// MODE 2: V^T permuted tiles            MODE 3: fp32 + bias (final)
template <int MODE>
__global__ __launch_bounds__(512) void k_gemm(
    const ushort* __restrict__ A, const ushort* __restrict__ BT,
    ushort* __restrict__ outB, float* __restrict__ outF,
    const float* __restrict__ bias, int M, int Kd, int N, size_t headStride) {
  __shared__ uint4 As4[128 * 8];
  __shared__ uint4 Bs4[64 * 8];
  int tid = threadIdx.x;
  int m0 = blockIdx.x * 128, n0 = blockIdx.y * 64;
  int wid = tid >> 6, lane = tid & 63;
  int wr = wid >> 1, wc = wid & 1;
  int lr = lane & 15, lg = lane >> 4;
  f32x4 acc[2][2] = {};

  for (int kt = 0; kt < Kd; kt += 64) {
    __syncthreads();
    {
      int id = tid;
#pragma unroll
      for (int i = 0; i < 2; ++i, id += 512) {
        int r = id >> 3, cc = id & 7;
        uint4 v = *(const uint4*)(A + (size_t)(m0 + r) * Kd + kt + cc * 8);
        As4[r * 8 + (cc ^ (r & 7))] = v;
      }
      int r = tid >> 3, cc = tid & 7;
      uint4 v = *(const uint4*)(BT + (size_t)(n0 + r) * Kd + kt + cc * 8);
      Bs4[r * 8 + (cc ^ (r & 7))] = v;
    }
    __syncthreads();
#pragma unroll
    for (int k0 = 0; k0 < 2; ++k0) {
      s16x8 a[2], b[2];
#pragma unroll
      for (int i = 0; i < 2; ++i) {
        int r = wr * 32 + i * 16 + lr;
        a[i] = *(const s16x8*)&As4[r * 8 + ((k0 * 4 + lg) ^ (r & 7))];
      }
#pragma unroll
      for (int j = 0; j < 2; ++j) {
        int r = wc * 32 + j * 16 + lr;
        b[j] = *(const s16x8*)&Bs4[r * 8 + ((k0 * 4 + lg) ^ (r & 7))];
      }
#pragma unroll
      for (int i = 0; i < 2; ++i)
#pragma unroll
        for (int j = 0; j < 2; ++j)
          acc[i][j] = __builtin_amdgcn_mfma_f32_16x16x32_bf16(a[i], b[j], acc[i][j], 0, 0, 0);
    }
  }
#pragma unroll
  for (int i = 0; i < 2; ++i)
#pragma unroll
    for (int j = 0; j < 2; ++j)
#pragma unroll
      for (int q = 0; q < 4; ++q) {
        int m = m0 + wr * 32 + i * 16 + lg * 4 + q;
        int n = n0 + wc * 32 + j * 16 + lr;
        float v = acc[i][j][q];
        if (MODE == 3) {
          outF[(size_t)m * N + n] = v + bias[n];
        } else if (MODE == 0) {
          outB[(size_t)(n >> 6) * headStride + (size_t)m * 64 + (n & 63)] = f2bf(v * SC2);
        } else if (MODE == 1) {
          int d = n & 63;
          outB[(size_t)(n >> 6) * headStride + (size_t)m * 64 +
               (((d >> 3) ^ (m & 7)) << 3) + (d & 7)] = f2bf(v);
        } else {  // MODE 2: V^T tiles, permuted positions
          int d = n & 63, tile = m >> 6, kl = m & 63;
          int c = vpos(kl);
          outB[((size_t)(n >> 6) * 128 + tile) * 4096 + (size_t)d * 64 +
               (((c >> 3) ^ (d & 7)) << 3) + (c & 7)] = f2bf(v);
        }
      }
}

// ---------------- flash attention (KV-split, static max, in-register P) ----------------
// grid 160*nsp flat = 8 XCDs x span; remapped so each XCD serves a contiguous
// logical span (KV footprint per XCD = 2.5MB at nsp=4 or 8 -> fits 4MB L2).
// 256 threads = 4 waves, wave owns 64 q-rows (4 row-blocks; block covers 256).
// K/V fragments loaded once per tile, reused across 4 row-block chains.
__global__ __launch_bounds__(256, 2) void k_attn(
    const ushort* __restrict__ qb,    // [H][L][64], pre-scaled by SC2
    const ushort* __restrict__ kb,    // [H][KVL][64] row-swizzled
    const ushort* __restrict__ vbT,   // [H][128][4096] V^T permuted tiles
    float* __restrict__ Op,           // [nsp][H][L][64] unnormalized
    float* __restrict__ lb,           // [nsp][H][L] row sums
    int nsp, int NT) {                // split count, tiles per split (128/nsp)
  __shared__ ushort Ks[2][4096];
  __shared__ ushort Vs[2][4096];

  int tid = threadIdx.x, wid = tid >> 6, lane = tid & 63;
  int lr = lane & 15, lg = lane >> 4;

  // XCD-contiguous remap: dispatch round-robins flat%8 across XCDs; give each
  // XCD a contiguous logical span (16 qblk x (10*nsp/8) (h,sp) pairs).
  int flat = blockIdx.x;
  int span = 20 * nsp;               // grid/8
  int f2 = (flat & 7) * span + (flat >> 3);
  int qblk = f2 & 15;
  int hs = f2 >> 4;                  // 0..10*nsp-1
  int h = hs % HH;
  int sp = hs / HH;
  int q0 = qblk * 256 + wid * 64;

  // Q fragments: 4 row-blocks x 2 k-chunks (B-operand: lane -> Q[row=lr][d=lg*8..])
  s16x8 qa[4][2];
#pragma unroll
  for (int i = 0; i < 4; ++i) {
    const ushort* qptr = qb + ((size_t)h * LL + q0 + i * 16 + lr) * DD + lg * 8;
    qa[i][0] = *(const s16x8*)qptr;
    qa[i][1] = *(const s16x8*)(qptr + 32);
  }

  // ones B-fragment for rowsum MFMA
  s16x8 ones;
#pragma unroll
  for (int i = 0; i < 8; ++i) ones[i] = (short)0x3F80;

  f32x4 o[4][4] = {};
  f32x4 ol[4] = {};

  const int t0 = sp * NT;
  const ushort* kh = kb + (size_t)h * KVL * DD + (size_t)t0 * 4096;
  const ushort* vh = vbT + (size_t)h * 128 * 4096 + (size_t)t0 * 4096;

  // prologue: stage tile 0 (2 K + 2 V gl16 per thread), wait, sync
#pragma unroll
  for (int i = 0; i < 2; ++i) {
    gl16(kh + (i * 256 + tid) * 8, &Ks[0][i * 2048 + wid * 512]);
    gl16(vh + (i * 256 + tid) * 8, &Vs[0][i * 2048 + wid * 512]);
  }
  asm volatile("s_waitcnt vmcnt(0)" ::: "memory");
  bar();

  for (int t = 0; t < NT; ++t) {
    if (t < NT - 1) {
      int nb = (t + 1) & 1;
      const ushort* gk = kh + (size_t)(t + 1) * 4096;
      const ushort* gv = vh + (size_t)(t + 1) * 4096;
#pragma unroll
      for (int i = 0; i < 2; ++i) {
        gl16(gk + (i * 256 + tid) * 8, &Ks[nb][i * 2048 + wid * 512]);
        gl16(gv + (i * 256 + tid) * 8, &Vs[nb][i * 2048 + wid * 512]);
      }
    }

    const ushort* Kc = Ks[t & 1];
    const ushort* Vc = Vs[t & 1];

    // S^T = K Q^T : 32 MFMA. Each K fragment feeds 4 row-block chains.
    // Lane (lg,lr), reg r of s[i][j]: S[q=q0+i*16+lr][kv=t*64+j*16+lg*4+r]
    f32x4 s[4][4] = {};
    __builtin_amdgcn_s_setprio(1);
#pragma unroll
    for (int k0 = 0; k0 < 2; ++k0) {
#pragma unroll
      for (int j = 0; j < 4; ++j) {
        int r = j * 16 + lr;
        s16x8 kf = *(const s16x8*)&Kc[r * 64 + (((k0 * 4 + lg) ^ (r & 7)) << 3)];
#pragma unroll
        for (int i = 0; i < 4; ++i)
          s[i][j] = __builtin_amdgcn_mfma_f32_16x16x32_bf16(kf, qa[i][k0], s[i][j], 0, 0, 0);
      }
    }
    __builtin_amdgcn_s_setprio(0);

    // P = exp2(S) (Q pre-scaled, static max), pack to bf16 pairs in-register
    uint w[4][4][2];
#pragma unroll
    for (int i = 0; i < 4; ++i)
#pragma unroll
      for (int j = 0; j < 4; ++j) {
        float p0 = fexp2(s[i][j][0]);
        float p1 = fexp2(s[i][j][1]);
        float p2 = fexp2(s[i][j][2]);
        float p3 = fexp2(s[i][j][3]);
        w[i][j][0] = cvtpk(p0, p1);
        w[i][j][1] = cvtpk(p2, p3);
      }

    // O += P V (32 MFMA) and rowsum l += P·1 (8 MFMA); V frag reused 4x
    __builtin_amdgcn_s_setprio(1);
#pragma unroll
    for (int k0 = 0; k0 < 2; ++k0) {
      s16x8 pa[4];
#pragma unroll
      for (int i = 0; i < 4; ++i) {
        uint4 u;
        u.x = w[i][2 * k0][0]; u.y = w[i][2 * k0][1];
        u.z = w[i][2 * k0 + 1][0]; u.w = w[i][2 * k0 + 1][1];
        pa[i] = __builtin_bit_cast(s16x8, u);
        ol[i] = __builtin_amdgcn_mfma_f32_16x16x32_bf16(pa[i], ones, ol[i], 0, 0, 0);
      }
#pragma unroll
      for (int j = 0; j < 4; ++j) {
        int r = j * 16 + lr;  // d row in V^T
        s16x8 bv = *(const s16x8*)&Vc[r * 64 + (((k0 * 4 + lg) ^ (r & 7)) << 3)];
#pragma unroll
        for (int i = 0; i < 4; ++i)
          o[i][j] = __builtin_amdgcn_mfma_f32_16x16x32_bf16(pa[i], bv, o[i][j], 0, 0, 0);
      }
    }
    __builtin_amdgcn_s_setprio(0);

    asm volatile("s_waitcnt vmcnt(0)" ::: "memory");  // next tile landed (issued a phase ago)
    bar();
  }

  // store unnormalized partials: row = q0 + i*16 + lg*4 + q, col = j*16 + lr
  size_t rbase = ((size_t)sp * HH + h) * LL;
#pragma unroll
  for (int i = 0; i < 4; ++i)
#pragma unroll
    for (int j = 0; j < 4; ++j)
#pragma unroll
      for (int q = 0; q < 4; ++q) {
        int row = q0 + i * 16 + lg * 4 + q;
        Op[(rbase + row) * 64 + j * 16 + lr] = o[i][j][q];
      }
  // rowsum: ol[i][q] identical across the 16 lr lanes; row = q0+i*16+lg*4+q
  if (lr == 0) {
#pragma unroll
    for (int i = 0; i < 4; ++i)
#pragma unroll
      for (int q = 0; q < 4; ++q)
        lb[rbase + q0 + i * 16 + lg * 4 + q] = ol[i][q];
  }
}

// ---------------- combine partials -> ctx bf16 [L][C] ----------------
__global__ __launch_bounds__(256) void k_comb(
    const float* __restrict__ Op, const float* __restrict__ lb,
    ushort* __restrict__ ctx, int nsp) {
  int t = threadIdx.x;
  int h = blockIdx.y;
  int row = blockIdx.x * 64 + (t >> 2);
  int d0 = (t & 3) * 16;

  float Lsum = 0.f;
  for (int s = 0; s < nsp; ++s)
    Lsum += lb[((size_t)s * HH + h) * LL + row];
  float inv = 1.0f / Lsum;

  float acc[16] = {};
  for (int s = 0; s < nsp; ++s) {
    size_t rb = (((size_t)s * HH + h) * LL + row) * 64 + d0;
#pragma unroll
    for (int i = 0; i < 4; ++i) {
      float4 v = *(const float4*)(Op + rb + i * 4);
      acc[i * 4 + 0] += v.x;
      acc[i * 4 + 1] += v.y;
      acc[i * 4 + 2] += v.z;
      acc[i * 4 + 3] += v.w;
    }
  }
  ushort ob[16];
#pragma unroll
  for (int i = 0; i < 16; ++i) ob[i] = f2bf(acc[i] * inv);
  ushort* dst = ctx + (size_t)row * CC + h * 64 + d0;
  *(uint4*)(dst + 0) = *(uint4*)(ob + 0);
  *(uint4*)(dst + 8) = *(uint4*)(ob + 8);
}

extern "C" void kernel_launch(void* const* d_in, const int* in_sizes, int n_in,
                              void* d_out, int out_size, void* d_ws, size_t ws_size,
                              hipStream_t stream) {
  const float* hs  = (const float*)d_in[0];
  const float* Kbg = (const float*)d_in[1];
  const float* Vbg = (const float*)d_in[2];
  const float* Wq  = (const float*)d_in[3];
  const float* Wk  = (const float*)d_in[4];
  const float* Wv  = (const float*)d_in[5];
  const float* Wo  = (const float*)d_in[6];
  const float* bo  = (const float*)d_in[7];
  float* out = (float*)d_out;

  // fixed-layout scratch
  char* p = (char*)d_ws;
  ushort* hs_b = (ushort*)p; p += (size_t)LL * CC * 2;
  ushort* WqT  = (ushort*)p; p += (size_t)CC * CC * 2;
  ushort* WkT  = (ushort*)p; p += (size_t)CC * CC * 2;
  ushort* WvT  = (ushort*)p; p += (size_t)CC * CC * 2;
  ushort* WoT  = (ushort*)p; p += (size_t)CC * CC * 2;
  ushort* qb   = (ushort*)p; p += (size_t)HH * LL * DD * 2;
  ushort* kb   = (ushort*)p; p += (size_t)HH * KVL * DD * 2;
  ushort* vbT  = (ushort*)p; p += (size_t)HH * KVL * DD * 2;
  ushort* ctxb = (ushort*)p; p += (size_t)LL * CC * 2;
  size_t fixedBytes = (size_t)(p - (char*)d_ws);

  // choose split by available workspace (deterministic in ws_size)
  int nsp = 8;
  {
    size_t need8 = fixedBytes + (size_t)8 * HH * LL * DD * 4 + (size_t)8 * HH * LL * 4;
    if (ws_size < need8) nsp = 4;
  }
  float* Opart = (float*)p;  p += (size_t)nsp * HH * LL * DD * 4;
  float* lbuf  = (float*)p;  p += (size_t)nsp * HH * LL * 4;
  int NT = 128 / nsp;

  int n4hs = LL * CC / 4;
  k_cvt_hs<<<(n4hs + 255) / 256, 256, 0, stream>>>(hs, hs_b, n4hs);
  k_wT<<<dim3(CC / 64, CC / 64), 256, 0, stream>>>(Wq, WqT);
  k_wT<<<dim3(CC / 64, CC / 64), 256, 0, stream>>>(Wk, WkT);
  k_wT<<<dim3(CC / 64, CC / 64), 256, 0, stream>>>(Wv, WvT);
  k_wT<<<dim3(CC / 64, CC / 64), 256, 0, stream>>>(Wo, WoT);
  int n4bg = HH * LL * DD / 4;
  k_cvt_bg<<<(n4bg + 255) / 256, 256, 0, stream>>>(Kbg, Vbg, kb, vbT, n4bg);

  k_gemm<0><<<dim3(LL / 128, CC / 64), 512, 0, stream>>>(
      hs_b, WqT, qb, nullptr, nullptr, LL, CC, CC, (size_t)LL * DD);
  k_gemm<1><<<dim3(LL / 128, CC / 64), 512, 0, stream>>>(
      hs_b, WkT, kb, nullptr, nullptr, LL, CC, CC, (size_t)KVL * DD);
  k_gemm<2><<<dim3(LL / 128, CC / 64), 512, 0, stream>>>(
      hs_b, WvT, vbT, nullptr, nullptr, LL, CC, CC, 0);

  k_attn<<<dim3(16 * HH * nsp), 256, 0, stream>>>(qb, kb, vbT, Opart, lbuf, nsp, NT);
  k_comb<<<dim3(LL / 64, HH), 256, 0, stream>>>(Opart, lbuf, ctxb, nsp);

  k_gemm<3><<<dim3(LL / 128, CC / 64), 512, 0, stream>>>(
      ctxb, WoT, nullptr, out, bo, LL, CC, CC, 0);
}

// Round 14
// 158.289 us; speedup vs baseline: 1.3734x; 1.1002x over previous
//
#include <hip/hip_runtime.h>
#include <stdint.h>

#define HH 10
#define DD 64
#define LL 4096
#define CC 640
#define KVL 8192
#define ALPHA 0.42f
#define SC2 0.1803368801111204f  // (1/sqrt(64)) * log2(e)

typedef __attribute__((ext_vector_type(8))) short s16x8;
typedef __attribute__((ext_vector_type(4))) float f32x4;

__device__ inline ushort f2bf(float f) {
  uint32_t u = __builtin_bit_cast(uint32_t, f);
  u += 0x7FFFu + ((u >> 16) & 1u);   // RNE
  return (ushort)(u >> 16);
}

__device__ inline uint cvtpk(float lo, float hi) {
  uint r;
  asm("v_cvt_pk_bf16_f32 %0, %1, %2" : "=v"(r) : "v"(lo), "v"(hi));
  return r;
}

__device__ inline float fexp2(float x) {
  float r;
  asm("v_exp_f32 %0, %1" : "=v"(r) : "v"(x));  // pure, schedulable
  return r;
}

__device__ inline void gl16(const ushort* g, ushort* l) {
  __builtin_amdgcn_global_load_lds(
      (const __attribute__((address_space(1))) uint32_t*)g,
      (__attribute__((address_space(3))) uint32_t*)l, 16, 0, 0);
}

__device__ inline void bar() {
  __builtin_amdgcn_sched_barrier(0);
  __builtin_amdgcn_s_barrier();
  __builtin_amdgcn_sched_barrier(0);
}

// V^T tile column position for kv-local row kl (0..63), matching the
// register layout of the swapped-QK^T P fragment (see k_attn):
// A-slot s=8*lg+m (within 32-block k0) must hold kv = 32*k0+16*(m>>2)+4*lg+(m&3).
// Inverse: p = (kl&32) | ((kl&12)<<1) | ((kl&16)>>2) | (kl&3)
__device__ inline int vpos(int kl) {
  return (kl & 32) | ((kl & 12) << 1) | ((kl & 16) >> 2) | (kl & 3);
}

// ---------------- prep: hs fp32 -> bf16 ----------------
__global__ void k_cvt_hs(const float* __restrict__ in, ushort* __restrict__ out, int n4) {
  int i = blockIdx.x * blockDim.x + threadIdx.x;
  if (i < n4) {
    float4 v = ((const float4*)in)[i];
    ushort4 o;
    o.x = f2bf(v.x); o.y = f2bf(v.y); o.z = f2bf(v.z); o.w = f2bf(v.w);
    ((ushort4*)out)[i] = o;
  }
}

// ---------------- prep: 4x W [K][N] fp32 -> WT [N][K] bf16 (z-batched) ----------------
// Identical body to the proven k_wT; z selects source and contiguous dst slice.
__global__ void k_wT4(const float* __restrict__ W0, const float* __restrict__ W1,
                      const float* __restrict__ W2, const float* __restrict__ W3,
                      ushort* __restrict__ WT) {
  __shared__ ushort t[64][65];
  const float* W = blockIdx.z == 0 ? W0 : blockIdx.z == 1 ? W1 : blockIdx.z == 2 ? W2 : W3;
  ushort* dst = WT + (size_t)blockIdx.z * CC * CC;
  int k0 = blockIdx.x * 64, n0 = blockIdx.y * 64;
  int tid = threadIdx.x;
#pragma unroll
  for (int i = 0; i < 4; ++i) {
    int id = tid + i * 256;
    int r = id >> 4, c4 = id & 15;
    float4 v = *(const float4*)(W + (size_t)(k0 + r) * CC + n0 + c4 * 4);
    t[r][c4 * 4 + 0] = f2bf(v.x);
    t[r][c4 * 4 + 1] = f2bf(v.y);
    t[r][c4 * 4 + 2] = f2bf(v.z);
    t[r][c4 * 4 + 3] = f2bf(v.w);
  }
  __syncthreads();
#pragma unroll
  for (int i = 0; i < 2; ++i) {
    int id = tid + i * 256;
    int n = id >> 3, cc = id & 7;
    ushort tmp[8];
#pragma unroll
    for (int j = 0; j < 8; ++j) tmp[j] = t[cc * 8 + j][n];
    *(uint4*)(dst + (size_t)(n0 + n) * CC + k0 + cc * 8) = *(uint4*)tmp;
  }
}

// ---------------- prep: background KV (rows L..KVL-1) ----------------
__global__ void k_cvt_bg(const float* __restrict__ Kbg, const float* __restrict__ Vbg,
                         ushort* __restrict__ kb, ushort* __restrict__ vbT, int n4) {
  int i = blockIdx.x * blockDim.x + threadIdx.x;
  if (i >= n4) return;
  int e = i * 4;
  int h = e / (LL * DD);
  int rem = e - h * (LL * DD);
  int kvl = rem >> 6;        // local row 0..4095
  int d0 = rem & 63;         // multiple of 4
  int kv = LL + kvl;         // global kv row
  float4 kf = ((const float4*)Kbg)[i];
  float4 vf = ((const float4*)Vbg)[i];
  {  // K: row-swizzled 16B chunks
    int chunk = d0 >> 3, off = d0 & 7;
    size_t kdst = ((size_t)h * KVL + kv) * 64 + (size_t)(((chunk ^ (kv & 7)) << 3) + off);
    ushort4 ok;
    ok.x = f2bf(ALPHA * kf.x); ok.y = f2bf(ALPHA * kf.y);
    ok.z = f2bf(ALPHA * kf.z); ok.w = f2bf(ALPHA * kf.w);
    *(ushort4*)(kb + kdst) = ok;
  }
  {  // V^T tiles: position-permuted + swizzled
    int tile = kv >> 6, kl = kv & 63;
    int c = vpos(kl);
    size_t vbase = ((size_t)h * 128 + tile) * 4096;
    float vv[4] = {vf.x, vf.y, vf.z, vf.w};
#pragma unroll
    for (int j = 0; j < 4; ++j) {
      int d = d0 + j;
      vbT[vbase + d * 64 + (((c >> 3) ^ (d & 7)) << 3) + (c & 7)] = f2bf(ALPHA * vv[j]);
    }
  }
}

// ---------------- fused QKV GEMM: z selects weight slice + epilogue ----------------
// Each z-slice is exactly the proven MODE 0/1/2 code on the same pointers.
__global__ __launch_bounds__(512) void k_gemmQKV(
    const ushort* __restrict__ A, const ushort* __restrict__ WT,
    ushort* __restrict__ qb, ushort* __restrict__ kb, ushort* __restrict__ vbT) {
  __shared__ uint4 As4[128 * 8];
  __shared__ uint4 Bs4[64 * 8];
  int tid = threadIdx.x;
  int m0 = blockIdx.x * 128, n0 = blockIdx.y * 64;
  int z = blockIdx.z;
  const ushort* BT = WT + (size_t)z * CC * CC;
  int wid = tid >> 6, lane = tid & 63;
  int wr = wid >> 1, wc = wid & 1;
  int lr = lane & 15, lg = lane >> 4;
  f32x4 acc[2][2] = {};

  for (int kt = 0; kt < CC; kt += 64) {
    __syncthreads();
    {
      int id = tid;
#pragma unroll
      for (int i = 0; i < 2; ++i, id += 512) {
        int r = id >> 3, cc = id & 7;
        uint4 v = *(const uint4*)(A + (size_t)(m0 + r) * CC + kt + cc * 8);
        As4[r * 8 + (cc ^ (r & 7))] = v;
      }
      int r = tid >> 3, cc = tid & 7;
      uint4 v = *(const uint4*)(BT + (size_t)(n0 + r) * CC + kt + cc * 8);
      Bs4[r * 8 + (cc ^ (r & 7))] = v;
    }
    __syncthreads();
#pragma unroll
    for (int k0 = 0; k0 < 2; ++k0) {
      s16x8 a[2], b[2];
#pragma unroll
      for (int i = 0; i < 2; ++i) {
        int r = wr * 32 + i * 16 + lr;
        a[i] = *(const s16x8*)&As4[r * 8 + ((k0 * 4 + lg) ^ (r & 7))];
      }
#pragma unroll
      for (int j = 0; j < 2; ++j) {
        int r = wc * 32 + j * 16 + lr;
        b[j] = *(const s16x8*)&Bs4[r * 8 + ((k0 * 4 + lg) ^ (r & 7))];
      }
#pragma unroll
      for (int i = 0; i < 2; ++i)
#pragma unroll
        for (int j = 0; j < 2; ++j)
          acc[i][j] = __builtin_amdgcn_mfma_f32_16x16x32_bf16(a[i], b[j], acc[i][j], 0, 0, 0);
    }
  }
#pragma unroll
  for (int i = 0; i < 2; ++i)
#pragma unroll
    for (int j = 0; j < 2; ++j)
#pragma unroll
      for (int q = 0; q < 4; ++q) {
        int m = m0 + wr * 32 + i * 16 + lg * 4 + q;
        int n = n0 + wc * 32 + j * 16 + lr;
        float v = acc[i][j][q];
        if (z == 0) {        // Q: head layout, scaled by SC2
          qb[(size_t)(n >> 6) * ((size_t)LL * DD) + (size_t)m * 64 + (n & 63)] = f2bf(v * SC2);
        } else if (z == 1) { // K: row-swizzled
          int d = n & 63;
          kb[(size_t)(n >> 6) * ((size_t)KVL * DD) + (size_t)m * 64 +
             (((d >> 3) ^ (m & 7)) << 3) + (d & 7)] = f2bf(v);
        } else {             // V: V^T permuted tiles
          int d = n & 63, tile = m >> 6, kl = m & 63;
          int c = vpos(kl);
          vbT[((size_t)(n >> 6) * 128 + tile) * 4096 + (size_t)d * 64 +
              (((c >> 3) ^ (d & 7)) << 3) + (c & 7)] = f2bf(v);
        }
      }
}

// ---------------- final GEMM: fp32 + bias ----------------
__global__ __launch_bounds__(512) void k_gemmO(
    const ushort* __restrict__ A, const ushort* __restrict__ BT,
    float* __restrict__ outF, const float* __restrict__ bias) {
  __shared__ uint4 As4[128 * 8];
  __shared__ uint4 Bs4[64 * 8];
  int tid = threadIdx.x;
  int m0 = blockIdx.x * 128, n0 = blockIdx.y * 64;
  int wid = tid >> 6, lane = tid & 63;
  int wr = wid >> 1, wc = wid & 1;
  int lr = lane & 15, lg = lane >> 4;
  f32x4 acc[2][2] = {};

  for (int kt = 0; kt < CC; kt += 64) {
    __syncthreads();
    {
      int id = tid;
#pragma unroll
      for (int i = 0; i < 2; ++i, id += 512) {
        int r = id >> 3, cc = id & 7;
        uint4 v = *(const uint4*)(A + (size_t)(m0 + r) * CC + kt + cc * 8);
        As4[r * 8 + (cc ^ (r & 7))] = v;
      }
      int r = tid >> 3, cc = tid & 7;
      uint4 v = *(const uint4*)(BT + (size_t)(n0 + r) * CC + kt + cc * 8);
      Bs4[r * 8 + (cc ^ (r & 7))] = v;
    }
    __syncthreads();
#pragma unroll
    for (int k0 = 0; k0 < 2; ++k0) {
      s16x8 a[2], b[2];
#pragma unroll
      for (int i = 0; i < 2; ++i) {
        int r = wr * 32 + i * 16 + lr;
        a[i] = *(const s16x8*)&As4[r * 8 + ((k0 * 4 + lg) ^ (r & 7))];
      }
#pragma unroll
      for (int j = 0; j < 2; ++j) {
        int r = wc * 32 + j * 16 + lr;
        b[j] = *(const s16x8*)&Bs4[r * 8 + ((k0 * 4 + lg) ^ (r & 7))];
      }
#pragma unroll
      for (int i = 0; i < 2; ++i)
#pragma unroll
        for (int j = 0; j < 2; ++j)
          acc[i][j] = __builtin_amdgcn_mfma_f32_16x16x32_bf16(a[i], b[j], acc[i][j], 0, 0, 0);
    }
  }
#pragma unroll
  for (int i = 0; i < 2; ++i)
#pragma unroll
    for (int j = 0; j < 2; ++j)
#pragma unroll
      for (int q = 0; q < 4; ++q) {
        int m = m0 + wr * 32 + i * 16 + lg * 4 + q;
        int n = n0 + wc * 32 + j * 16 + lr;
        outF[(size_t)m * CC + n] = acc[i][j][q] + bias[n];
      }
}

// ---------------- flash attention (KV-split, static max, in-register P) ----------------
// R10-proven monolithic schedule: grid 160*nsp flat, XCD-contiguous remap,
// 256 threads = 4 waves, wave owns 64 q-rows (4 row-blocks; block covers 256).
// K/V fragments loaded once per tile, reused across 4 row-block chains.
__global__ __launch_bounds__(256, 2) void k_attn(
    const ushort* __restrict__ qb,    // [H][L][64], pre-scaled by SC2
    const ushort* __restrict__ kb,    // [H][KVL][64] row-swizzled
    const ushort* __restrict__ vbT,   // [H][128][4096] V^T permuted tiles
    float* __restrict__ Op,           // [nsp][H][L][64] unnormalized
    float* __restrict__ lb,           // [nsp][H][L] row sums
    int nsp, int NT) {                // split count, tiles per split (128/nsp)
  __shared__ ushort Ks[2][4096];
  __shared__ ushort Vs[2][4096];

  int tid = threadIdx.x, wid = tid >> 6, lane = tid & 63;
  int lr = lane & 15, lg = lane >> 4;

  // XCD-contiguous remap: dispatch round-robins flat%8 across XCDs; give each
  // XCD a contiguous logical span (16 qblk x (10*nsp/8) (h,sp) pairs).
  int flat = blockIdx.x;
  int span = 20 * nsp;               // grid/8
  int f2 = (flat & 7) * span + (flat >> 3);
  int qblk = f2 & 15;
  int hs = f2 >> 4;                  // 0..10*nsp-1
  int h = hs % HH;
  int sp = hs / HH;
  int q0 = qblk * 256 + wid * 64;

  // Q fragments: 4 row-blocks x 2 k-chunks (B-operand: lane -> Q[row=lr][d=lg*8..])
  s16x8 qa[4][2];
#pragma unroll
  for (int i = 0; i < 4; ++i) {
    const ushort* qptr = qb + ((size_t)h * LL + q0 + i * 16 + lr) * DD + lg * 8;
    qa[i][0] = *(const s16x8*)qptr;
    qa[i][1] = *(const s16x8*)(qptr + 32);
  }

  // ones B-fragment for rowsum MFMA
  s16x8 ones;
#pragma unroll
  for (int i = 0; i < 8; ++i) ones[i] = (short)0x3F80;

  f32x4 o[4][4] = {};
  f32x4 ol[4] = {};

  const int t0 = sp * NT;
  const ushort* kh = kb + (size_t)h * KVL * DD + (size_t)t0 * 4096;
  const ushort* vh = vbT + (size_t)h * 128 * 4096 + (size_t)t0 * 4096;

  // prologue: stage tile 0 (2 K + 2 V gl16 per thread), wait, sync
#pragma unroll
  for (int i = 0; i < 2; ++i) {
    gl16(kh + (i * 256 + tid) * 8, &Ks[0][i * 2048 + wid * 512]);
    gl16(vh + (i * 256 + tid) * 8, &Vs[0][i * 2048 + wid * 512]);
  }
  asm volatile("s_waitcnt vmcnt(0)" ::: "memory");
  bar();

  for (int t = 0; t < NT; ++t) {
    if (t < NT - 1) {
      int nb = (t + 1) & 1;
      const ushort* gk = kh + (size_t)(t + 1) * 4096;
      const ushort* gv = vh + (size_t)(t + 1) * 4096;
#pragma unroll
      for (int i = 0; i < 2; ++i) {
        gl16(gk + (i * 256 + tid) * 8, &Ks[nb][i * 2048 + wid * 512]);
        gl16(gv + (i * 256 + tid) * 8, &Vs[nb][i * 2048 + wid * 512]);
      }
    }

    const ushort* Kc = Ks[t & 1];
    const ushort* Vc = Vs[t & 1];

    // S^T = K Q^T : 32 MFMA. Each K fragment feeds 4 row-block chains.
    // Lane (lg,lr), reg r of s[i][j]: S[q=q0+i*16+lr][kv=t*64+j*16+lg*4+r]
    f32x4 s[4][4] = {};
    __builtin_amdgcn_s_setprio(1);
#pragma unroll
    for (int k0 = 0; k0 < 2; ++k0) {
#pragma unroll
      for (int j = 0; j < 4; ++j) {
        int r = j * 16 + lr;
        s16x8 kf = *(const s16x8*)&Kc[r * 64 + (((k0 * 4 + lg) ^ (r & 7)) << 3)];
#pragma unroll
        for (int i = 0; i < 4; ++i)
          s[i][j] = __builtin_amdgcn_mfma_f32_16x16x32_bf16(kf, qa[i][k0], s[i][j], 0, 0, 0);
      }
    }
    __builtin_amdgcn_s_setprio(0);

    // P = exp2(S) (Q pre-scaled, static max), pack to bf16 pairs in-register
    uint w[4][4][2];
#pragma unroll
    for (int i = 0; i < 4; ++i)
#pragma unroll
      for (int j = 0; j < 4; ++j) {
        float p0 = fexp2(s[i][j][0]);
        float p1 = fexp2(s[i][j][1]);
        float p2 = fexp2(s[i][j][2]);
        float p3 = fexp2(s[i][j][3]);
        w[i][j][0] = cvtpk(p0, p1);
        w[i][j][1] = cvtpk(p2, p3);
      }

    // O += P V (32 MFMA) and rowsum l += P·1 (8 MFMA); V frag reused 4x
    __builtin_amdgcn_s_setprio(1);
#pragma unroll
    for (int k0 = 0; k0 < 2; ++k0) {
      s16x8 pa[4];
#pragma unroll
      for (int i = 0; i < 4; ++i) {
        uint4 u;
        u.x = w[i][2 * k0][0]; u.y = w[i][2 * k0][1];
        u.z = w[i][2 * k0 + 1][0]; u.w = w[i][2 * k0 + 1][1];
        pa[i] = __builtin_bit_cast(s16x8, u);
        ol[i] = __builtin_amdgcn_mfma_f32_16x16x32_bf16(pa[i], ones, ol[i], 0, 0, 0);
      }
#pragma unroll
      for (int j = 0; j < 4; ++j) {
        int r = j * 16 + lr;  // d row in V^T
        s16x8 bv = *(const s16x8*)&Vc[r * 64 + (((k0 * 4 + lg) ^ (r & 7)) << 3)];
#pragma unroll
        for (int i = 0; i < 4; ++i)
          o[i][j] = __builtin_amdgcn_mfma_f32_16x16x32_bf16(pa[i], bv, o[i][j], 0, 0, 0);
      }
    }
    __builtin_amdgcn_s_setprio(0);

    asm volatile("s_waitcnt vmcnt(0)" ::: "memory");  // next tile landed (issued a phase ago)
    bar();
  }

  // store unnormalized partials: row = q0 + i*16 + lg*4 + q, col = j*16 + lr
  size_t rbase = ((size_t)sp * HH + h) * LL;
#pragma unroll
  for (int i = 0; i < 4; ++i)
#pragma unroll
    for (int j = 0; j < 4; ++j)
#pragma unroll
      for (int q = 0; q < 4; ++q) {
        int row = q0 + i * 16 + lg * 4 + q;
        Op[(rbase + row) * 64 + j * 16 + lr] = o[i][j][q];
      }
  // rowsum: ol[i][q] identical across the 16 lr lanes; row = q0+i*16+lg*4+q
  if (lr == 0) {
#pragma unroll
    for (int i = 0; i < 4; ++i)
#pragma unroll
      for (int q = 0; q < 4; ++q)
        lb[rbase + q0 + i * 16 + lg * 4 + q] = ol[i][q];
  }
}

// ---------------- combine partials -> ctx bf16 [L][C] ----------------
__global__ __launch_bounds__(256) void k_comb(
    const float* __restrict__ Op, const float* __restrict__ lb,
    ushort* __restrict__ ctx, int nsp) {
  int t = threadIdx.x;
  int h = blockIdx.y;
  int row = blockIdx.x * 64 + (t >> 2);
  int d0 = (t & 3) * 16;

  float Lsum = 0.f;
  for (int s = 0; s < nsp; ++s)
    Lsum += lb[((size_t)s * HH + h) * LL + row];
  float inv = 1.0f / Lsum;

  float acc[16] = {};
  for (int s = 0; s < nsp; ++s) {
    size_t rb = (((size_t)s * HH + h) * LL + row) * 64 + d0;
#pragma unroll
    for (int i = 0; i < 4; ++i) {
      float4 v = *(const float4*)(Op + rb + i * 4);
      acc[i * 4 + 0] += v.x;
      acc[i * 4 + 1] += v.y;
      acc[i * 4 + 2] += v.z;
      acc[i * 4 + 3] += v.w;
    }
  }
  ushort ob[16];
#pragma unroll
  for (int i = 0; i < 16; ++i) ob[i] = f2bf(acc[i] * inv);
  ushort* dst = ctx + (size_t)row * CC + h * 64 + d0;
  *(uint4*)(dst + 0) = *(uint4*)(ob + 0);
  *(uint4*)(dst + 8) = *(uint4*)(ob + 8);
}

extern "C" void kernel_launch(void* const* d_in, const int* in_sizes, int n_in,
                              void* d_out, int out_size, void* d_ws, size_t ws_size,
                              hipStream_t stream) {
  const float* hs  = (const float*)d_in[0];
  const float* Kbg = (const float*)d_in[1];
  const float* Vbg = (const float*)d_in[2];
  const float* Wq  = (const float*)d_in[3];
  const float* Wk  = (const float*)d_in[4];
  const float* Wv  = (const float*)d_in[5];
  const float* Wo  = (const float*)d_in[6];
  const float* bo  = (const float*)d_in[7];
  float* out = (float*)d_out;

  // fixed-layout scratch
  char* p = (char*)d_ws;
  ushort* hs_b = (ushort*)p; p += (size_t)LL * CC * 2;
  ushort* WqT  = (ushort*)p; p += (size_t)CC * CC * 2;   // WqT..WoT contiguous
  ushort* WkT  = (ushort*)p; p += (size_t)CC * CC * 2;
  ushort* WvT  = (ushort*)p; p += (size_t)CC * CC * 2;
  ushort* WoT  = (ushort*)p; p += (size_t)CC * CC * 2;
  ushort* qb   = (ushort*)p; p += (size_t)HH * LL * DD * 2;
  ushort* kb   = (ushort*)p; p += (size_t)HH * KVL * DD * 2;
  ushort* vbT  = (ushort*)p; p += (size_t)HH * KVL * DD * 2;
  ushort* ctxb = (ushort*)p; p += (size_t)LL * CC * 2;
  size_t fixedBytes = (size_t)(p - (char*)d_ws);
  (void)WkT; (void)WvT;

  // choose split by available workspace (deterministic in ws_size)
  int nsp = 8;
  {
    size_t need8 = fixedBytes + (size_t)8 * HH * LL * DD * 4 + (size_t)8 * HH * LL * 4;
    if (ws_size < need8) nsp = 4;
  }
  float* Opart = (float*)p;  p += (size_t)nsp * HH * LL * DD * 4;
  float* lbuf  = (float*)p;  p += (size_t)nsp * HH * LL * 4;
  int NT = 128 / nsp;

  int n4hs = LL * CC / 4;
  k_cvt_hs<<<(n4hs + 255) / 256, 256, 0, stream>>>(hs, hs_b, n4hs);
  k_wT4<<<dim3(CC / 64, CC / 64, 4), 256, 0, stream>>>(Wq, Wk, Wv, Wo, WqT);
  int n4bg = HH * LL * DD / 4;
  k_cvt_bg<<<(n4bg + 255) / 256, 256, 0, stream>>>(Kbg, Vbg, kb, vbT, n4bg);

  k_gemmQKV<<<dim3(LL / 128, CC / 64, 3), 512, 0, stream>>>(hs_b, WqT, qb, kb, vbT);

  k_attn<<<dim3(16 * HH * nsp), 256, 0, stream>>>(qb, kb, vbT, Opart, lbuf, nsp, NT);
  k_comb<<<dim3(LL / 64, HH), 256, 0, stream>>>(Opart, lbuf, ctxb, nsp);

  k_gemmO<<<dim3(LL / 128, CC / 64), 512, 0, stream>>>(ctxb, WoT, out, bo);
}

// Round 15
// 152.836 us; speedup vs baseline: 1.4224x; 1.0357x over previous
//
#include <hip/hip_runtime.h>
#include <stdint.h>

#define HH 10
#define DD 64
#define LL 4096
#define CC 640
#define KVL 8192
#define ALPHA 0.42f
#define SC2 0.1803368801111204f  // (1/sqrt(64)) * log2(e)

typedef __attribute__((ext_vector_type(8))) short s16x8;
typedef __attribute__((ext_vector_type(4))) float f32x4;

__device__ inline ushort f2bf(float f) {
  uint32_t u = __builtin_bit_cast(uint32_t, f);
  u += 0x7FFFu + ((u >> 16) & 1u);   // RNE
  return (ushort)(u >> 16);
}

__device__ inline uint cvtpk(float lo, float hi) {
  uint r;
  asm("v_cvt_pk_bf16_f32 %0, %1, %2" : "=v"(r) : "v"(lo), "v"(hi));
  return r;
}

__device__ inline float fexp2(float x) {
  float r;
  asm("v_exp_f32 %0, %1" : "=v"(r) : "v"(x));  // pure, schedulable
  return r;
}

__device__ inline void gl16(const ushort* g, ushort* l) {
  __builtin_amdgcn_global_load_lds(
      (const __attribute__((address_space(1))) uint32_t*)g,
      (__attribute__((address_space(3))) uint32_t*)l, 16, 0, 0);
}

__device__ inline void bar() {
  __builtin_amdgcn_sched_barrier(0);
  __builtin_amdgcn_s_barrier();
  __builtin_amdgcn_sched_barrier(0);
}

// V^T tile column position for kv-local row kl (0..63), matching the
// register layout of the swapped-QK^T P fragment (see k_attn):
// A-slot s=8*lg+m (within 32-block k0) must hold kv = 32*k0+16*(m>>2)+4*lg+(m&3).
// Inverse: p = (kl&32) | ((kl&12)<<1) | ((kl&16)>>2) | (kl&3)
__device__ inline int vpos(int kl) {
  return (kl & 32) | ((kl & 12) << 1) | ((kl & 16) >> 2) | (kl & 3);
}

// ---------------- prep: hs fp32 -> bf16 ----------------
__global__ void k_cvt_hs(const float* __restrict__ in, ushort* __restrict__ out, int n4) {
  int i = blockIdx.x * blockDim.x + threadIdx.x;
  if (i < n4) {
    float4 v = ((const float4*)in)[i];
    ushort4 o;
    o.x = f2bf(v.x); o.y = f2bf(v.y); o.z = f2bf(v.z); o.w = f2bf(v.w);
    ((ushort4*)out)[i] = o;
  }
}

// ---------------- prep: 4x W [K][N] fp32 -> WT [N][K] bf16 (z-batched) ----------------
__global__ void k_wT4(const float* __restrict__ W0, const float* __restrict__ W1,
                      const float* __restrict__ W2, const float* __restrict__ W3,
                      ushort* __restrict__ WT) {
  __shared__ ushort t[64][65];
  const float* W = blockIdx.z == 0 ? W0 : blockIdx.z == 1 ? W1 : blockIdx.z == 2 ? W2 : W3;
  ushort* dst = WT + (size_t)blockIdx.z * CC * CC;
  int k0 = blockIdx.x * 64, n0 = blockIdx.y * 64;
  int tid = threadIdx.x;
#pragma unroll
  for (int i = 0; i < 4; ++i) {
    int id = tid + i * 256;
    int r = id >> 4, c4 = id & 15;
    float4 v = *(const float4*)(W + (size_t)(k0 + r) * CC + n0 + c4 * 4);
    t[r][c4 * 4 + 0] = f2bf(v.x);
    t[r][c4 * 4 + 1] = f2bf(v.y);
    t[r][c4 * 4 + 2] = f2bf(v.z);
    t[r][c4 * 4 + 3] = f2bf(v.w);
  }
  __syncthreads();
#pragma unroll
  for (int i = 0; i < 2; ++i) {
    int id = tid + i * 256;
    int n = id >> 3, cc = id & 7;
    ushort tmp[8];
#pragma unroll
    for (int j = 0; j < 8; ++j) tmp[j] = t[cc * 8 + j][n];
    *(uint4*)(dst + (size_t)(n0 + n) * CC + k0 + cc * 8) = *(uint4*)tmp;
  }
}

// ---------------- prep: background KV (rows L..KVL-1) ----------------
__global__ void k_cvt_bg(const float* __restrict__ Kbg, const float* __restrict__ Vbg,
                         ushort* __restrict__ kb, ushort* __restrict__ vbT, int n4) {
  int i = blockIdx.x * blockDim.x + threadIdx.x;
  if (i >= n4) return;
  int e = i * 4;
  int h = e / (LL * DD);
  int rem = e - h * (LL * DD);
  int kvl = rem >> 6;        // local row 0..4095
  int d0 = rem & 63;         // multiple of 4
  int kv = LL + kvl;         // global kv row
  float4 kf = ((const float4*)Kbg)[i];
  float4 vf = ((const float4*)Vbg)[i];
  {  // K: row-swizzled 16B chunks
    int chunk = d0 >> 3, off = d0 & 7;
    size_t kdst = ((size_t)h * KVL + kv) * 64 + (size_t)(((chunk ^ (kv & 7)) << 3) + off);
    ushort4 ok;
    ok.x = f2bf(ALPHA * kf.x); ok.y = f2bf(ALPHA * kf.y);
    ok.z = f2bf(ALPHA * kf.z); ok.w = f2bf(ALPHA * kf.w);
    *(ushort4*)(kb + kdst) = ok;
  }
  {  // V^T tiles: position-permuted + swizzled
    int tile = kv >> 6, kl = kv & 63;
    int c = vpos(kl);
    size_t vbase = ((size_t)h * 128 + tile) * 4096;
    float vv[4] = {vf.x, vf.y, vf.z, vf.w};
#pragma unroll
    for (int j = 0; j < 4; ++j) {
      int d = d0 + j;
      vbT[vbase + d * 64 + (((c >> 3) ^ (d & 7)) << 3) + (c & 7)] = f2bf(ALPHA * vv[j]);
    }
  }
}

// ---------------- fused QKV GEMM: z selects weight slice + epilogue ----------------
__global__ __launch_bounds__(512) void k_gemmQKV(
    const ushort* __restrict__ A, const ushort* __restrict__ WT,
    ushort* __restrict__ qb, ushort* __restrict__ kb, ushort* __restrict__ vbT) {
  __shared__ uint4 As4[128 * 8];
  __shared__ uint4 Bs4[64 * 8];
  int tid = threadIdx.x;
  int m0 = blockIdx.x * 128, n0 = blockIdx.y * 64;
  int z = blockIdx.z;
  const ushort* BT = WT + (size_t)z * CC * CC;
  int wid = tid >> 6, lane = tid & 63;
  int wr = wid >> 1, wc = wid & 1;
  int lr = lane & 15, lg = lane >> 4;
  f32x4 acc[2][2] = {};

  for (int kt = 0; kt < CC; kt += 64) {
    __syncthreads();
    {
      int id = tid;
#pragma unroll
      for (int i = 0; i < 2; ++i, id += 512) {
        int r = id >> 3, cc = id & 7;
        uint4 v = *(const uint4*)(A + (size_t)(m0 + r) * CC + kt + cc * 8);
        As4[r * 8 + (cc ^ (r & 7))] = v;
      }
      int r = tid >> 3, cc = tid & 7;
      uint4 v = *(const uint4*)(BT + (size_t)(n0 + r) * CC + kt + cc * 8);
      Bs4[r * 8 + (cc ^ (r & 7))] = v;
    }
    __syncthreads();
#pragma unroll
    for (int k0 = 0; k0 < 2; ++k0) {
      s16x8 a[2], b[2];
#pragma unroll
      for (int i = 0; i < 2; ++i) {
        int r = wr * 32 + i * 16 + lr;
        a[i] = *(const s16x8*)&As4[r * 8 + ((k0 * 4 + lg) ^ (r & 7))];
      }
#pragma unroll
      for (int j = 0; j < 2; ++j) {
        int r = wc * 32 + j * 16 + lr;
        b[j] = *(const s16x8*)&Bs4[r * 8 + ((k0 * 4 + lg) ^ (r & 7))];
      }
#pragma unroll
      for (int i = 0; i < 2; ++i)
#pragma unroll
        for (int j = 0; j < 2; ++j)
          acc[i][j] = __builtin_amdgcn_mfma_f32_16x16x32_bf16(a[i], b[j], acc[i][j], 0, 0, 0);
    }
  }
#pragma unroll
  for (int i = 0; i < 2; ++i)
#pragma unroll
    for (int j = 0; j < 2; ++j)
#pragma unroll
      for (int q = 0; q < 4; ++q) {
        int m = m0 + wr * 32 + i * 16 + lg * 4 + q;
        int n = n0 + wc * 32 + j * 16 + lr;
        float v = acc[i][j][q];
        if (z == 0) {        // Q: head layout, scaled by SC2
          qb[(size_t)(n >> 6) * ((size_t)LL * DD) + (size_t)m * 64 + (n & 63)] = f2bf(v * SC2);
        } else if (z == 1) { // K: row-swizzled
          int d = n & 63;
          kb[(size_t)(n >> 6) * ((size_t)KVL * DD) + (size_t)m * 64 +
             (((d >> 3) ^ (m & 7)) << 3) + (d & 7)] = f2bf(v);
        } else {             // V: V^T permuted tiles
          int d = n & 63, tile = m >> 6, kl = m & 63;
          int c = vpos(kl);
          vbT[((size_t)(n >> 6) * 128 + tile) * 4096 + (size_t)d * 64 +
              (((c >> 3) ^ (d & 7)) << 3) + (c & 7)] = f2bf(v);
        }
      }
}

// ---------------- final GEMM: fp32 + bias ----------------
__global__ __launch_bounds__(512) void k_gemmO(
    const ushort* __restrict__ A, const ushort* __restrict__ BT,
    float* __restrict__ outF, const float* __restrict__ bias) {
  __shared__ uint4 As4[128 * 8];
  __shared__ uint4 Bs4[64 * 8];
  int tid = threadIdx.x;
  int m0 = blockIdx.x * 128, n0 = blockIdx.y * 64;
  int wid = tid >> 6, lane = tid & 63;
  int wr = wid >> 1, wc = wid & 1;
  int lr = lane & 15, lg = lane >> 4;
  f32x4 acc[2][2] = {};

  for (int kt = 0; kt < CC; kt += 64) {
    __syncthreads();
    {
      int id = tid;
#pragma unroll
      for (int i = 0; i < 2; ++i, id += 512) {
        int r = id >> 3, cc = id & 7;
        uint4 v = *(const uint4*)(A + (size_t)(m0 + r) * CC + kt + cc * 8);
        As4[r * 8 + (cc ^ (r & 7))] = v;
      }
      int r = tid >> 3, cc = tid & 7;
      uint4 v = *(const uint4*)(BT + (size_t)(n0 + r) * CC + kt + cc * 8);
      Bs4[r * 8 + (cc ^ (r & 7))] = v;
    }
    __syncthreads();
#pragma unroll
    for (int k0 = 0; k0 < 2; ++k0) {
      s16x8 a[2], b[2];
#pragma unroll
      for (int i = 0; i < 2; ++i) {
        int r = wr * 32 + i * 16 + lr;
        a[i] = *(const s16x8*)&As4[r * 8 + ((k0 * 4 + lg) ^ (r & 7))];
      }
#pragma unroll
      for (int j = 0; j < 2; ++j) {
        int r = wc * 32 + j * 16 + lr;
        b[j] = *(const s16x8*)&Bs4[r * 8 + ((k0 * 4 + lg) ^ (r & 7))];
      }
#pragma unroll
      for (int i = 0; i < 2; ++i)
#pragma unroll
        for (int j = 0; j < 2; ++j)
          acc[i][j] = __builtin_amdgcn_mfma_f32_16x16x32_bf16(a[i], b[j], acc[i][j], 0, 0, 0);
    }
  }
#pragma unroll
  for (int i = 0; i < 2; ++i)
#pragma unroll
    for (int j = 0; j < 2; ++j)
#pragma unroll
      for (int q = 0; q < 4; ++q) {
        int m = m0 + wr * 32 + i * 16 + lg * 4 + q;
        int n = n0 + wc * 32 + j * 16 + lr;
        outF[(size_t)m * CC + n] = acc[i][j][q] + bias[n];
      }
}

// ---------------- flash attention (KV-split, static max, in-register P) ----------------
// R10-proven monolithic per-64kv body, now over 128-kv SUPERTILES:
// stage two contiguous 64-kv tiles (K rows and V^T tiles are contiguous),
// process the two halves sequentially with the unchanged body, and pay
// vmcnt(0)+barrier once per 128 kv. LDS 64 KB (2 blocks/CU; regs bind first).
__global__ __launch_bounds__(256, 2) void k_attn(
    const ushort* __restrict__ qb,    // [H][L][64], pre-scaled by SC2
    const ushort* __restrict__ kb,    // [H][KVL][64] row-swizzled
    const ushort* __restrict__ vbT,   // [H][128][4096] V^T permuted tiles
    float* __restrict__ Op,           // [nsp][H][L][64] unnormalized
    float* __restrict__ lb,           // [nsp][H][L] row sums
    int nsp, int NT) {                // split count, SUPERTILES per split
  __shared__ ushort Ks[2][8192];
  __shared__ ushort Vs[2][8192];

  int tid = threadIdx.x, wid = tid >> 6, lane = tid & 63;
  int lr = lane & 15, lg = lane >> 4;

  // XCD-contiguous remap: dispatch round-robins flat%8 across XCDs; give each
  // XCD a contiguous logical span (16 qblk x (10*nsp/8) (h,sp) pairs).
  int flat = blockIdx.x;
  int span = 20 * nsp;               // grid/8
  int f2 = (flat & 7) * span + (flat >> 3);
  int qblk = f2 & 15;
  int hs = f2 >> 4;                  // 0..10*nsp-1
  int h = hs % HH;
  int sp = hs / HH;
  int q0 = qblk * 256 + wid * 64;

  // Q fragments: 4 row-blocks x 2 k-chunks (B-operand: lane -> Q[row=lr][d=lg*8..])
  s16x8 qa[4][2];
#pragma unroll
  for (int i = 0; i < 4; ++i) {
    const ushort* qptr = qb + ((size_t)h * LL + q0 + i * 16 + lr) * DD + lg * 8;
    qa[i][0] = *(const s16x8*)qptr;
    qa[i][1] = *(const s16x8*)(qptr + 32);
  }

  // ones B-fragment for rowsum MFMA
  s16x8 ones;
#pragma unroll
  for (int i = 0; i < 8; ++i) ones[i] = (short)0x3F80;

  f32x4 o[4][4] = {};
  f32x4 ol[4] = {};

  const ushort* kh = kb + (size_t)h * KVL * DD + (size_t)sp * NT * 8192;
  const ushort* vh = vbT + (size_t)h * 128 * 4096 + (size_t)sp * NT * 8192;

  // proven 64-kv body (pure function of the two LDS half-tile pointers)
  auto body = [&](const ushort* Kc, const ushort* Vc) {
    // S^T = K Q^T : 32 MFMA. Each K fragment feeds 4 row-block chains.
    f32x4 s[4][4] = {};
    __builtin_amdgcn_s_setprio(1);
#pragma unroll
    for (int k0 = 0; k0 < 2; ++k0) {
#pragma unroll
      for (int j = 0; j < 4; ++j) {
        int r = j * 16 + lr;
        s16x8 kf = *(const s16x8*)&Kc[r * 64 + (((k0 * 4 + lg) ^ (r & 7)) << 3)];
#pragma unroll
        for (int i = 0; i < 4; ++i)
          s[i][j] = __builtin_amdgcn_mfma_f32_16x16x32_bf16(kf, qa[i][k0], s[i][j], 0, 0, 0);
      }
    }
    __builtin_amdgcn_s_setprio(0);

    // P = exp2(S) (Q pre-scaled, static max), pack to bf16 pairs in-register
    uint w[4][4][2];
#pragma unroll
    for (int i = 0; i < 4; ++i)
#pragma unroll
      for (int j = 0; j < 4; ++j) {
        float p0 = fexp2(s[i][j][0]);
        float p1 = fexp2(s[i][j][1]);
        float p2 = fexp2(s[i][j][2]);
        float p3 = fexp2(s[i][j][3]);
        w[i][j][0] = cvtpk(p0, p1);
        w[i][j][1] = cvtpk(p2, p3);
      }

    // O += P V (32 MFMA) and rowsum l += P·1 (8 MFMA); V frag reused 4x
    __builtin_amdgcn_s_setprio(1);
#pragma unroll
    for (int k0 = 0; k0 < 2; ++k0) {
      s16x8 pa[4];
#pragma unroll
      for (int i = 0; i < 4; ++i) {
        uint4 u;
        u.x = w[i][2 * k0][0]; u.y = w[i][2 * k0][1];
        u.z = w[i][2 * k0 + 1][0]; u.w = w[i][2 * k0 + 1][1];
        pa[i] = __builtin_bit_cast(s16x8, u);
        ol[i] = __builtin_amdgcn_mfma_f32_16x16x32_bf16(pa[i], ones, ol[i], 0, 0, 0);
      }
#pragma unroll
      for (int j = 0; j < 4; ++j) {
        int r = j * 16 + lr;  // d row in V^T
        s16x8 bv = *(const s16x8*)&Vc[r * 64 + (((k0 * 4 + lg) ^ (r & 7)) << 3)];
#pragma unroll
        for (int i = 0; i < 4; ++i)
          o[i][j] = __builtin_amdgcn_mfma_f32_16x16x32_bf16(pa[i], bv, o[i][j], 0, 0, 0);
      }
    }
    __builtin_amdgcn_s_setprio(0);
  };

  // prologue: stage supertile 0 (4 K + 4 V gl16 per thread), wait, sync
#pragma unroll
  for (int i = 0; i < 4; ++i) {
    gl16(kh + (i * 256 + tid) * 8, &Ks[0][i * 2048 + wid * 512]);
    gl16(vh + (i * 256 + tid) * 8, &Vs[0][i * 2048 + wid * 512]);
  }
  asm volatile("s_waitcnt vmcnt(0)" ::: "memory");
  bar();

  for (int t = 0; t < NT; ++t) {
    if (t < NT - 1) {
      int nb = (t + 1) & 1;
      const ushort* gk = kh + (size_t)(t + 1) * 8192;
      const ushort* gv = vh + (size_t)(t + 1) * 8192;
#pragma unroll
      for (int i = 0; i < 4; ++i) {
        gl16(gk + (i * 256 + tid) * 8, &Ks[nb][i * 2048 + wid * 512]);
        gl16(gv + (i * 256 + tid) * 8, &Vs[nb][i * 2048 + wid * 512]);
      }
    }

    const ushort* Kc = Ks[t & 1];
    const ushort* Vc = Vs[t & 1];

    body(Kc, Vc);                    // kv half 0 (rows 0..63 of supertile)
    body(Kc + 4096, Vc + 4096);      // kv half 1 (rows 64..127)

    asm volatile("s_waitcnt vmcnt(0)" ::: "memory");  // next supertile landed
    bar();
  }

  // store unnormalized partials: row = q0 + i*16 + lg*4 + q, col = j*16 + lr
  size_t rbase = ((size_t)sp * HH + h) * LL;
#pragma unroll
  for (int i = 0; i < 4; ++i)
#pragma unroll
    for (int j = 0; j < 4; ++j)
#pragma unroll
      for (int q = 0; q < 4; ++q) {
        int row = q0 + i * 16 + lg * 4 + q;
        Op[(rbase + row) * 64 + j * 16 + lr] = o[i][j][q];
      }
  // rowsum: ol[i][q] identical across the 16 lr lanes; row = q0+i*16+lg*4+q
  if (lr == 0) {
#pragma unroll
    for (int i = 0; i < 4; ++i)
#pragma unroll
      for (int q = 0; q < 4; ++q)
        lb[rbase + q0 + i * 16 + lg * 4 + q] = ol[i][q];
  }
}

// ---------------- combine partials -> ctx bf16 [L][C] ----------------
__global__ __launch_bounds__(256) void k_comb(
    const float* __restrict__ Op, const float* __restrict__ lb,
    ushort* __restrict__ ctx, int nsp) {
  int t = threadIdx.x;
  int h = blockIdx.y;
  int row = blockIdx.x * 64 + (t >> 2);
  int d0 = (t & 3) * 16;

  float Lsum = 0.f;
  for (int s = 0; s < nsp; ++s)
    Lsum += lb[((size_t)s * HH + h) * LL + row];
  float inv = 1.0f / Lsum;

  float acc[16] = {};
  for (int s = 0; s < nsp; ++s) {
    size_t rb = (((size_t)s * HH + h) * LL + row) * 64 + d0;
#pragma unroll
    for (int i = 0; i < 4; ++i) {
      float4 v = *(const float4*)(Op + rb + i * 4);
      acc[i * 4 + 0] += v.x;
      acc[i * 4 + 1] += v.y;
      acc[i * 4 + 2] += v.z;
      acc[i * 4 + 3] += v.w;
    }
  }
  ushort ob[16];
#pragma unroll
  for (int i = 0; i < 16; ++i) ob[i] = f2bf(acc[i] * inv);
  ushort* dst = ctx + (size_t)row * CC + h * 64 + d0;
  *(uint4*)(dst + 0) = *(uint4*)(ob + 0);
  *(uint4*)(dst + 8) = *(uint4*)(ob + 8);
}

extern "C" void kernel_launch(void* const* d_in, const int* in_sizes, int n_in,
                              void* d_out, int out_size, void* d_ws, size_t ws_size,
                              hipStream_t stream) {
  const float* hs  = (const float*)d_in[0];
  const float* Kbg = (const float*)d_in[1];
  const float* Vbg = (const float*)d_in[2];
  const float* Wq  = (const float*)d_in[3];
  const float* Wk  = (const float*)d_in[4];
  const float* Wv  = (const float*)d_in[5];
  const float* Wo  = (const float*)d_in[6];
  const float* bo  = (const float*)d_in[7];
  float* out = (float*)d_out;

  // fixed-layout scratch
  char* p = (char*)d_ws;
  ushort* hs_b = (ushort*)p; p += (size_t)LL * CC * 2;
  ushort* WqT  = (ushort*)p; p += (size_t)CC * CC * 2;   // WqT..WoT contiguous
  ushort* WkT  = (ushort*)p; p += (size_t)CC * CC * 2;
  ushort* WvT  = (ushort*)p; p += (size_t)CC * CC * 2;
  ushort* WoT  = (ushort*)p; p += (size_t)CC * CC * 2;
  ushort* qb   = (ushort*)p; p += (size_t)HH * LL * DD * 2;
  ushort* kb   = (ushort*)p; p += (size_t)HH * KVL * DD * 2;
  ushort* vbT  = (ushort*)p; p += (size_t)HH * KVL * DD * 2;
  ushort* ctxb = (ushort*)p; p += (size_t)LL * CC * 2;
  size_t fixedBytes = (size_t)(p - (char*)d_ws);
  (void)WkT; (void)WvT;

  // choose split by available workspace (deterministic in ws_size)
  int nsp = 8;
  {
    size_t need8 = fixedBytes + (size_t)8 * HH * LL * DD * 4 + (size_t)8 * HH * LL * 4;
    if (ws_size < need8) nsp = 4;
  }
  float* Opart = (float*)p;  p += (size_t)nsp * HH * LL * DD * 4;
  float* lbuf  = (float*)p;  p += (size_t)nsp * HH * LL * 4;
  int NT = KVL / nsp / 128;  // supertiles (128 kv each) per split

  int n4hs = LL * CC / 4;
  k_cvt_hs<<<(n4hs + 255) / 256, 256, 0, stream>>>(hs, hs_b, n4hs);
  k_wT4<<<dim3(CC / 64, CC / 64, 4), 256, 0, stream>>>(Wq, Wk, Wv, Wo, WqT);
  int n4bg = HH * LL * DD / 4;
  k_cvt_bg<<<(n4bg + 255) / 256, 256, 0, stream>>>(Kbg, Vbg, kb, vbT, n4bg);

  k_gemmQKV<<<dim3(LL / 128, CC / 64, 3), 512, 0, stream>>>(hs_b, WqT, qb, kb, vbT);

  k_attn<<<dim3(16 * HH * nsp), 256, 0, stream>>>(qb, kb, vbT, Opart, lbuf, nsp, NT);
  k_comb<<<dim3(LL / 64, HH), 256, 0, stream>>>(Opart, lbuf, ctxb, nsp);

  k_gemmO<<<dim3(LL / 128, CC / 64), 512, 0, stream>>>(ctxb, WoT, out, bo);
}